// Round 15
// baseline (78.452 us; speedup 1.0000x reference)
//
#include <hip/hip_runtime.h>
#include <math.h>

#define BB 4
#define CC 64
#define CRR 8
#define NN 4096

typedef __attribute__((ext_vector_type(8))) short bf16x8;
typedef __attribute__((ext_vector_type(4))) float f32x4;

__device__ inline float bf2f(ushort u) {
    union { uint i; float f; } v; v.i = (uint)u << 16; return v.f;
}
__device__ inline ushort f2bf(float f) {
    uint u = __builtin_bit_cast(uint, f);
    u = (u + 0x7FFFu + ((u >> 16) & 1u)) >> 16;
    return (ushort)u;
}
__device__ inline uint bfpack2(float a, float b) {
    uint ua = __builtin_bit_cast(uint, a);
    uint ub = __builtin_bit_cast(uint, b);
    ua = (ua + 0x7FFFu + ((ua >> 16) & 1u)) >> 16;
    ub = (ub + 0x7FFFu + ((ub >> 16) & 1u)) & 0xFFFF0000u;
    return ua | ub;
}
// 1-op truncating bf16 pair pack: bytes [b.3,b.2,a.3,a.2]
__device__ inline uint pkrtz(float a, float b) {
    return __builtin_amdgcn_perm(__builtin_bit_cast(uint, b),
                                 __builtin_bit_cast(uint, a), 0x07060302u);
}
// native 2^x (single v_exp_f32; inputs bounded |x| < 30 here)
__device__ inline float fexp2(float x) {
#if __has_builtin(__builtin_amdgcn_exp2f)
    return __builtin_amdgcn_exp2f(x);
#else
    float r; asm("v_exp_f32 %0, %1" : "=v"(r) : "v"(x)); return r;
#endif
}

// x2p padded pixel-major: [b][py 70][px 70][ci 64] bf16, pad=3
#define X2P_B 313600   // 70*70*64

// ---------------------------------------------------------------------------
// Producer: f = conv1x1(x,w1,b1) * log2(e), g = conv1x1(x,w2,b2),
//           hh = conv1x1(x,w3,b3).  b = bid&3 (XCD-local batches).
// ---------------------------------------------------------------------------
__global__ __launch_bounds__(256) void produce_fgh(
    const float* __restrict__ x,
    const float* __restrict__ w1, const float* __restrict__ b1,
    const float* __restrict__ w2, const float* __restrict__ b2,
    const float* __restrict__ w3, const float* __restrict__ b3,
    ushort* __restrict__ fT, ushort* __restrict__ gT, ushort* __restrict__ hhb)
{
    const float LOG2E = 1.4426950408889634f;
    int t = threadIdx.x;
    int b = blockIdx.x & 3;
    int n = ((blockIdx.x >> 2) << 6) + (t & 63);
    int og = __builtin_amdgcn_readfirstlane(t >> 6);  // wave-uniform

    const float* xb = x + ((size_t)b << 18) + n;
    float xv[64];
#pragma unroll
    for (int c = 0; c < 64; ++c) xv[c] = xb[(size_t)c << 12];

    if (og == 0) {
        ushort fo[8], go[8];
#pragma unroll
        for (int k = 0; k < 8; ++k) {
            float a1 = b1[k], a2 = b2[k];
#pragma unroll
            for (int c = 0; c < 64; ++c) {
                a1 = fmaf(w1[k * 64 + c], xv[c], a1);
                a2 = fmaf(w2[k * 64 + c], xv[c], a2);
            }
            fo[k] = f2bf(a1 * LOG2E); go[k] = f2bf(a2);
        }
        uint4 fq = make_uint4((uint)fo[0] | ((uint)fo[1] << 16),
                              (uint)fo[2] | ((uint)fo[3] << 16),
                              (uint)fo[4] | ((uint)fo[5] << 16),
                              (uint)fo[6] | ((uint)fo[7] << 16));
        uint4 gq = make_uint4((uint)go[0] | ((uint)go[1] << 16),
                              (uint)go[2] | ((uint)go[3] << 16),
                              (uint)go[4] | ((uint)go[5] << 16),
                              (uint)go[6] | ((uint)go[7] << 16));
        *(uint4*)&fT[((size_t)b << 15) + (size_t)n * 8] = fq;
        *(uint4*)&gT[((size_t)b << 15) + (size_t)n * 8] = gq;
#pragma unroll
        for (int k = 0; k < 4; ++k) {
            float a = b3[k];
#pragma unroll
            for (int c = 0; c < 64; ++c) a = fmaf(w3[k * 64 + c], xv[c], a);
            hhb[((size_t)b << 18) + ((size_t)k << 12) + n] = f2bf(a);
        }
    } else {
        int c0 = og * 20 - 16;  // 4, 24, 44
#pragma unroll
        for (int k = 0; k < 20; ++k) {
            float a = b3[c0 + k];
#pragma unroll
            for (int c = 0; c < 64; ++c) a = fmaf(w3[(c0 + k) * 64 + c], xv[c], a);
            hhb[((size_t)b << 18) + ((size_t)(c0 + k) << 12) + n] = f2bf(a);
        }
    }
}

// ---------------------------------------------------------------------------
// Weight transform + w6->bf16 + x2p halo zero, one kernel.
// ---------------------------------------------------------------------------
__global__ __launch_bounds__(256) void wtz_kernel(
    const float* __restrict__ w4, const float* __restrict__ w5,
    const float* __restrict__ w6,
    ushort* __restrict__ Wt, ushort* __restrict__ w6b, ushort* __restrict__ x2p)
{
    int bid = blockIdx.x;
    int t = threadIdx.x;
    if (bid < 128) {
        int conv = bid >> 6, co = bid & 63;
        const float* W = conv ? w5 : w4;
        for (int i = t; i < 3136; i += 256) {
            int ci = i / 49, kk = i - ci * 49;
            Wt[(((size_t)(conv * 64 + co)) * 49 + kk) * 64 + ci] = f2bf(W[co * 3136 + i]);
        }
    } else if (bid == 128) {
#pragma unroll
        for (int k = 0; k < 16; ++k) {
            int i = k * 256 + t;
            w6b[i] = f2bf(w6[i]);
        }
    } else {
        int gid = (bid - 129) * 256 + t;
        if (gid >= 4 * 804) return;
        int b = gid / 804;
        int i = gid - b * 804;
        int py, px;
        if (i < 210) { py = i / 70; px = i - py * 70; }
        else if (i < 420) { int j = i - 210; int r = j / 70; py = 67 + r; px = j - r * 70; }
        else { int j = i - 420; int r = j / 6; py = 3 + r; int c = j - r * 6; px = c < 3 ? c : 64 + c; }
        ushort* p = x2p + (size_t)b * X2P_B + (size_t)(py * 70 + px) * 64;
        uint4 z = make_uint4(0, 0, 0, 0);
#pragma unroll
        for (int k = 0; k < 8; ++k) *(uint4*)(p + k * 8) = z;
    }
}

// ---------------------------------------------------------------------------
// Fused MFMA flash attention + h2 epilogue, 8-wave full-m design:
// 512 thr = 8 waves; wave w owns ALL 64 m and private n-slice [512w,512w+512),
// processed as 8 blocks of 64 n. Private hh + P LDS buffers -> NO barriers
// in the main loop; hf reads shared across the 4 mt tiles (4x less LDS).
// 8-way fp32 combine in LDS afterwards. grid = B*64.
// ---------------------------------------------------------------------------
__global__ __launch_bounds__(512) void attn_kernel(
    const ushort* __restrict__ fT, const ushort* __restrict__ gT,
    const ushort* __restrict__ hhb, const ushort* __restrict__ w6b,
    const float* __restrict__ b6,
    ushort* __restrict__ x2p, ushort* __restrict__ h2b)
{
    __shared__ __align__(16) char smem[150528];
    // main-loop views (per-wave private):
    ushort* hhW = (ushort*)smem;                 // [8 wave][4096]  64 KB
    ushort* Pw  = (ushort*)(smem + 65536);       // [8 wave][4096]  64 KB
    // combine views (post-barrier reuse):
    float* Acc = (float*)smem;                   // [8 w][64 m][68]  139,264 B
    float* Lq  = (float*)(smem + 139264);        // [8][64]          2,048 B
    ushort* x2s = (ushort*)(smem + 141312);      // [64 m][72]       9,216 B

    int t = threadIdx.x;
    int w = t >> 6, l = t & 63;
    int ml = l & 15, g = l >> 4;
    int b = blockIdx.x & 3;                      // XCD-local batch
    int mt0 = blockIdx.x >> 2;
    int m0 = mt0 << 6;

    const ushort* fTb = fT + ((size_t)b << 15) + (size_t)(w * 512) * 8;
    const ushort* gTb = gT + ((size_t)b << 15);
    const ushort* hrow = hhb + ((size_t)b << 18) + (size_t)l * 4096 + w * 512;

    const bf16x8 z8 = {0, 0, 0, 0, 0, 0, 0, 0};
    const f32x4 z4 = {0.f, 0.f, 0.f, 0.f};

    // B-fragments for scores: one per 16-m tile, held in registers.
    bf16x8 gfrag[4];
#pragma unroll
    for (int mt = 0; mt < 4; ++mt) {
        gfrag[mt] = *(const bf16x8*)(gTb + (size_t)(m0 + 16 * mt + ml) * 8);
        if (g != 0) gfrag[mt] = z8;
    }

    ushort* hhme = hhW + w * 4096;
    char* pme = (char*)(Pw + w * 4096);
    int swz = (ml & 7) << 4;

    // prologue: stage block 0 (lane l stages hh row c=l, 64 n = 8 uint4)
    uint4 hreg[8];
#pragma unroll
    for (int i = 0; i < 8; ++i) hreg[i] = *(const uint4*)(hrow + i * 8);
    bf16x8 afc[4];
#pragma unroll
    for (int nt = 0; nt < 4; ++nt)
        afc[nt] = *(const bf16x8*)(fTb + (size_t)(16 * nt + ml) * 8);
#pragma unroll
    for (int i = 0; i < 8; ++i) *(uint4*)&hhme[i * 512 + l * 8] = hreg[i];

    f32x4 acc[4][4];   // [ct][mt]
#pragma unroll
    for (int ct = 0; ct < 4; ++ct)
#pragma unroll
        for (int mt = 0; mt < 4; ++mt) acc[ct][mt] = z4;
    float rsum[4] = {0.f, 0.f, 0.f, 0.f};

    for (int bk = 0; bk < 8; ++bk) {
        uint4 hnx[8];
        bf16x8 afn[4];
        if (bk < 7) {
            int base = (bk + 1) * 64;
#pragma unroll
            for (int i = 0; i < 8; ++i)
                hnx[i] = *(const uint4*)(hrow + base + i * 8);
#pragma unroll
            for (int nt = 0; nt < 4; ++nt)
                afn[nt] = *(const bf16x8*)(fTb + (size_t)(base + 16 * nt + ml) * 8);
        }

        // ---- scores + exp2 + P store (private swizzled [m][n] buffer) ----
#pragma unroll
        for (int nt = 0; nt < 4; ++nt) {
#pragma unroll
            for (int mt = 0; mt < 4; ++mt) {
                f32x4 Sv = __builtin_amdgcn_mfma_f32_16x16x32_bf16(
                    afc[nt], gfrag[mt], z4, 0, 0, 0);
                float p0 = fexp2(Sv[0]);
                float p1 = fexp2(Sv[1]);
                float p2 = fexp2(Sv[2]);
                float p3 = fexp2(Sv[3]);
                rsum[mt] += (p0 + p1) + (p2 + p3);
                uint off = (uint)(((16 * mt + ml) * 128 + (16 * nt + 4 * g) * 2) ^ swz);
                *(uint2*)(pme + off) = make_uint2(pkrtz(p0, p1), pkrtz(p2, p3));
            }
        }

        // ---- PV: hf shared across mt (the 4x LDS saving) ----
#pragma unroll
        for (int kk = 0; kk < 2; ++kk) {
#pragma unroll
            for (int mt = 0; mt < 4; ++mt) {
                uint off = (uint)(((16 * mt + ml) * 128 + (32 * kk + 8 * g) * 2) ^ swz);
                bf16x8 pf = *(const bf16x8*)(pme + off);
#pragma unroll
                for (int ct = 0; ct < 4; ++ct) {
                    bf16x8 hf = *(const bf16x8*)&hhme[(kk * 4 + g) * 512 + (16 * ct + ml) * 8];
                    acc[ct][mt] = __builtin_amdgcn_mfma_f32_16x16x32_bf16(
                        hf, pf, acc[ct][mt], 0, 0, 0);
                }
            }
        }

        if (bk < 7) {
#pragma unroll
            for (int i = 0; i < 8; ++i) *(uint4*)&hhme[i * 512 + l * 8] = hnx[i];
#pragma unroll
            for (int nt = 0; nt < 4; ++nt) afc[nt] = afn[nt];
        }
    }

    // per-m denominators: reduce over g groups
#pragma unroll
    for (int mt = 0; mt < 4; ++mt) {
        rsum[mt] += __shfl_xor(rsum[mt], 16);
        rsum[mt] += __shfl_xor(rsum[mt], 32);
    }

    __syncthreads();   // all waves done with hh/P before Acc reuse

#pragma unroll
    for (int ct = 0; ct < 4; ++ct)
#pragma unroll
        for (int mt = 0; mt < 4; ++mt)
            *(f32x4*)&Acc[(size_t)(w * 64 + 16 * mt + ml) * 68 + 16 * ct + 4 * g] = acc[ct][mt];
    if (g == 0) {
#pragma unroll
        for (int mt = 0; mt < 4; ++mt) Lq[w * 64 + 16 * mt + ml] = rsum[mt];
    }
    __syncthreads();

    // ---- combine 8 wave-partials; write x2p + x2s ----
    {
        int m = t >> 3, c0 = (t & 7) << 3;
        float Lt = 0.f;
#pragma unroll
        for (int wv = 0; wv < 8; ++wv) Lt += Lq[wv * 64 + m];
        float rL = 1.f / Lt;
        f32x4 sa = z4, sb = z4;
#pragma unroll
        for (int wv = 0; wv < 8; ++wv) {
            const float* ap = &Acc[(size_t)(wv * 64 + m) * 68 + c0];
            sa += *(const f32x4*)ap;
            sb += *(const f32x4*)(ap + 4);
        }
        uint4 pk = make_uint4(bfpack2(sa[0] * rL, sa[1] * rL),
                              bfpack2(sa[2] * rL, sa[3] * rL),
                              bfpack2(sb[0] * rL, sb[1] * rL),
                              bfpack2(sb[2] * rL, sb[3] * rL));
        int px = m + 3, py = mt0 + 3;
        *(uint4*)(x2p + (size_t)b * X2P_B + (size_t)(py * 70 + px) * 64 + c0) = pk;
        *(uint4*)&x2s[m * 72 + c0] = pk;
    }
    __syncthreads();

    // ---- h2 epilogue: wave w -> d-tile w>>1, two m-subtiles ----
    {
        int dt = w >> 1;
#pragma unroll
        for (int mi = 0; mi < 2; ++mi) {
            int mq = (w & 1) * 2 + mi;
            f32x4 hacc = z4;
#pragma unroll
            for (int kk = 0; kk < 2; ++kk) {
                bf16x8 xf = *(const bf16x8*)&x2s[(mq * 16 + ml) * 72 + 32 * kk + 8 * g];
                bf16x8 wf = *(const bf16x8*)(w6b + (size_t)(16 * dt + ml) * 64 + 32 * kk + 8 * g);
                hacc = __builtin_amdgcn_mfma_f32_16x16x32_bf16(wf, xf, hacc, 0, 0, 0);
            }
            ushort* h2row = h2b + ((size_t)b << 18) + (m0 + mq * 16 + ml);
#pragma unroll
            for (int r = 0; r < 4; ++r) {
                int d = 16 * dt + 4 * g + r;
                h2row[(size_t)d << 12] = f2bf(hacc[r] + b6[d]);
            }
        }
    }
}

// ---------------------------------------------------------------------------
// 7x7 stride-4 conv, single kernel (R12 structure, unchanged).
// ---------------------------------------------------------------------------
__global__ __launch_bounds__(448) void conv7_kernel(
    const ushort* __restrict__ x2p, const ushort* __restrict__ Wt,
    const float* __restrict__ b4, const float* __restrict__ b5,
    float* __restrict__ f2, float* __restrict__ g2)
{
    __shared__ float red[7][512];   // 14 KB
    int t = threadIdx.x;
    int l = t & 63, ky = t >> 6;    // wave = ky 0..6
    int ml = l & 15, g = l >> 4;
    int bid = blockIdx.x;
    int bc = bid & 7;               // XCD-local (b,conv)
    int sub = bid >> 3;             // 0..31
    int ct = sub & 3, oh = sub >> 2;  // co-tile, 32-opix half
    int conv = bc & 1, b = bc >> 1;

    int co0 = ct * 16;
    const ushort* wb = Wt + (size_t)conv * 200704
                     + (size_t)(co0 + ml) * 3136 + (size_t)(ky * 7) * 64 + g * 8;
    const ushort* xbase = x2p + (size_t)b * X2P_B + g * 8;

    int pixoff[2];
#pragma unroll
    for (int s = 0; s < 2; ++s) {
        int opix = oh * 32 + s * 16 + ml;
        int oy = opix >> 4, ox = opix & 15;
        pixoff[s] = ((oy * 4 + ky) * 70 + ox * 4) * 64;
    }

    const f32x4 z4 = {0.f, 0.f, 0.f, 0.f};
    f32x4 acc[2] = {z4, z4};

#pragma unroll
    for (int kx = 0; kx < 7; ++kx) {
#pragma unroll
        for (int ci0 = 0; ci0 < 64; ci0 += 32) {
            bf16x8 av = *(const bf16x8*)(wb + kx * 64 + ci0);
#pragma unroll
            for (int s = 0; s < 2; ++s) {
                bf16x8 bv = *(const bf16x8*)(xbase + pixoff[s] + kx * 64 + ci0);
                acc[s] = __builtin_amdgcn_mfma_f32_16x16x32_bf16(av, bv, acc[s], 0, 0, 0);
            }
        }
    }

#pragma unroll
    for (int s = 0; s < 2; ++s)
#pragma unroll
        for (int r = 0; r < 4; ++r)
            red[ky][(4 * g + r) * 32 + s * 16 + ml] = acc[s][r];
    __syncthreads();

    const float* bias = conv ? b5 : b4;
    float* y = conv ? g2 : f2;
    for (int idx = t; idx < 512; idx += 448) {
        float s = red[0][idx];
        s += red[1][idx]; s += red[2][idx]; s += red[3][idx];
        s += red[4][idx]; s += red[5][idx]; s += red[6][idx];
        int co = co0 + (idx >> 5);
        int opix = oh * 32 + (idx & 31);
        y[((size_t)(b * 64 + co) << 8) + opix] = s + bias[co];
    }
}

// ---------------------------------------------------------------------------
// s2 + softmax, register-blocked fp32 (R13 structure, unchanged).
// ---------------------------------------------------------------------------
__global__ __launch_bounds__(256) void s2_softmax_kernel(
    const float* __restrict__ f2, const float* __restrict__ g2,
    float* __restrict__ beta2)
{
    __shared__ __align__(16) float g2t[256][8];   // [n][4d + pad] 8 KB
    __shared__ __align__(16) float part[16][64][4]; // 16 KB
    __shared__ __align__(16) float s2f[64][4];    // 1 KB
    __shared__ float mx4[4], rs4[4];
    int t = threadIdx.x;
    int b = blockIdx.x & 3;
    int d0 = (blockIdx.x >> 2) << 2;   // 4 d per wg

    {   // stage g2t[n][dd]
        int dd = t & 3, n0 = (t >> 2) << 2;
        const float* gp = g2 + ((size_t)(b * 64 + d0 + dd) << 8) + n0;
        float4 v = *(const float4*)gp;
        g2t[n0 + 0][dd] = v.x; g2t[n0 + 1][dd] = v.y;
        g2t[n0 + 2][dd] = v.z; g2t[n0 + 3][dd] = v.w;
    }
    __syncthreads();

    int c0 = (t & 15) << 2, nq = t >> 4;
    float acc[4][4];
#pragma unroll
    for (int i = 0; i < 4; ++i)
#pragma unroll
        for (int j = 0; j < 4; ++j) acc[i][j] = 0.f;
    const float* fb = f2 + ((size_t)(b * 64) << 8);
#pragma unroll 4
    for (int i = 0; i < 16; ++i) {
        int n = (nq << 4) + ((i + nq) & 15);   // staggered: bank-spread + broadcast
        float4 gv = *(const float4*)&g2t[n][0];
        float fv0 = fb[(c0 + 0) * 256 + n];
        float fv1 = fb[(c0 + 1) * 256 + n];
        float fv2 = fb[(c0 + 2) * 256 + n];
        float fv3 = fb[(c0 + 3) * 256 + n];
        acc[0][0] = fmaf(fv0, gv.x, acc[0][0]); acc[0][1] = fmaf(fv0, gv.y, acc[0][1]);
        acc[0][2] = fmaf(fv0, gv.z, acc[0][2]); acc[0][3] = fmaf(fv0, gv.w, acc[0][3]);
        acc[1][0] = fmaf(fv1, gv.x, acc[1][0]); acc[1][1] = fmaf(fv1, gv.y, acc[1][1]);
        acc[1][2] = fmaf(fv1, gv.z, acc[1][2]); acc[1][3] = fmaf(fv1, gv.w, acc[1][3]);
        acc[2][0] = fmaf(fv2, gv.x, acc[2][0]); acc[2][1] = fmaf(fv2, gv.y, acc[2][1]);
        acc[2][2] = fmaf(fv2, gv.z, acc[2][2]); acc[2][3] = fmaf(fv2, gv.w, acc[2][3]);
        acc[3][0] = fmaf(fv3, gv.x, acc[3][0]); acc[3][1] = fmaf(fv3, gv.y, acc[3][1]);
        acc[3][2] = fmaf(fv3, gv.z, acc[3][2]); acc[3][3] = fmaf(fv3, gv.w, acc[3][3]);
    }
#pragma unroll
    for (int i = 0; i < 4; ++i)
        *(float4*)&part[nq][c0 + i][0] =
            make_float4(acc[i][0], acc[i][1], acc[i][2], acc[i][3]);
    __syncthreads();

    if (t < 64) {   // reduce 16 n-partials for row c = t
        int c = t;
        float4 s = make_float4(0.f, 0.f, 0.f, 0.f);
#pragma unroll
        for (int q2 = 0; q2 < 16; ++q2) {
            float4 v = *(const float4*)&part[q2][c][0];
            s.x += v.x; s.y += v.y; s.z += v.z; s.w += v.w;
        }
        *(float4*)&s2f[c][0] = s;
    }
    __syncthreads();
    if (t < 4) {    // softmax stats over c for column d0+t
        float mxv = s2f[0][t];
        for (int c = 1; c < 64; ++c) mxv = fmaxf(mxv, s2f[c][t]);
        float sm = 0.f;
        for (int c = 0; c < 64; ++c) sm += __expf(s2f[c][t] - mxv);
        mx4[t] = mxv; rs4[t] = 1.f / sm;
    }
    __syncthreads();
    {
        int c = t >> 2, dd = t & 3;
        beta2[((size_t)b << 12) + c * 64 + d0 + dd] =
            __expf(s2f[c][dd] - mx4[dd]) * rs4[dd];
    }
}

// ---------------------------------------------------------------------------
// o2 + residual via MFMA (R13 structure, unchanged).
// ---------------------------------------------------------------------------
__global__ __launch_bounds__(256) void o2_residual_kernel(
    const ushort* __restrict__ h2b, const float* __restrict__ beta2,
    const float* __restrict__ x, float* __restrict__ out)
{
    __shared__ __align__(16) ushort bt[64][68];   // beta2^T hi  [d][c]
    __shared__ __align__(16) ushort btl[64][68];  // beta2^T lo
    __shared__ __align__(16) ushort hn[64][68];   // h2^T [n][c]
    int t = threadIdx.x;
    int b = blockIdx.x & 3;
    int n0 = (blockIdx.x >> 2) << 6;
    int l = t & 63, w = t >> 6;
    int ml = l & 15, g = l >> 4;

    {   // stage: thread c = t>>2, 16-chunk = t&3
        int c = t >> 2, o16 = (t & 3) << 4;
        const float* bp = beta2 + ((size_t)b << 12) + c * 64 + o16;
#pragma unroll
        for (int i = 0; i < 16; i += 4) {
            float4 v = *(const float4*)(bp + i);
            float vv[4] = {v.x, v.y, v.z, v.w};
#pragma unroll
            for (int k = 0; k < 4; ++k) {
                ushort hi = f2bf(vv[k]);
                bt[o16 + i + k][c] = hi;
                btl[o16 + i + k][c] = f2bf(vv[k] - bf2f(hi));
            }
        }
        const ushort* hp = h2b + ((size_t)(b * 64 + c) << 12) + n0 + o16;
#pragma unroll
        for (int i = 0; i < 16; i += 8) {
            uint4 hv = *(const uint4*)(hp + i);
            const ushort* hs = (const ushort*)&hv;
#pragma unroll
            for (int k = 0; k < 8; ++k) hn[o16 + i + k][c] = hs[k];
        }
    }
    __syncthreads();

    const f32x4 z4 = {0.f, 0.f, 0.f, 0.f};
    f32x4 acc[4] = {z4, z4, z4, z4};
#pragma unroll
    for (int kk = 0; kk < 2; ++kk) {
        bf16x8 ah = *(const bf16x8*)&bt[w * 16 + ml][kk * 32 + g * 8];
        bf16x8 al = *(const bf16x8*)&btl[w * 16 + ml][kk * 32 + g * 8];
#pragma unroll
        for (int nt = 0; nt < 4; ++nt) {
            bf16x8 bv = *(const bf16x8*)&hn[nt * 16 + ml][kk * 32 + g * 8];
            acc[nt] = __builtin_amdgcn_mfma_f32_16x16x32_bf16(ah, bv, acc[nt], 0, 0, 0);
            acc[nt] = __builtin_amdgcn_mfma_f32_16x16x32_bf16(al, bv, acc[nt], 0, 0, 0);
        }
    }

#pragma unroll
    for (int nt = 0; nt < 4; ++nt)
#pragma unroll
        for (int r = 0; r < 4; ++r) {
            int d = w * 16 + g * 4 + r;
            int n = n0 + nt * 16 + ml;
            size_t o = ((size_t)(b * 64 + d) << 12) + n;
            out[o] = acc[nt][r] + x[o];
        }
}

// ---------------------------------------------------------------------------
extern "C" void kernel_launch(void* const* d_in, const int* in_sizes, int n_in,
                              void* d_out, int out_size, void* d_ws, size_t ws_size,
                              hipStream_t stream)
{
    const float* x  = (const float*)d_in[0];
    const float* w1 = (const float*)d_in[1];
    const float* b1 = (const float*)d_in[2];
    const float* w2 = (const float*)d_in[3];
    const float* b2 = (const float*)d_in[4];
    const float* w3 = (const float*)d_in[5];
    const float* b3 = (const float*)d_in[6];
    const float* w4 = (const float*)d_in[7];
    const float* b4 = (const float*)d_in[8];
    const float* w5 = (const float*)d_in[9];
    const float* b5 = (const float*)d_in[10];
    const float* w6 = (const float*)d_in[11];
    const float* b6 = (const float*)d_in[12];
    float* out = (float*)d_out;

    ushort* u = (ushort*)d_ws;
    ushort* fT  = u;                  // 131072 elems
    ushort* gT  = fT + 131072;        // 131072
    ushort* hhb = gT + 131072;        // 1048576
    ushort* x2p = hhb + 1048576;      // 1254400 (4*70*70*64), padded
    ushort* h2b = x2p + 1254400;      // 1048576
    ushort* Wt  = h2b + 1048576;      // 401408 (2*64*49*64)
    ushort* w6b = Wt + 401408;        // 4096
    float* fr    = (float*)(w6b + 4096);
    float* f2    = fr;                // 65536
    float* g2    = fr + 65536;        // 65536
    float* beta2 = fr + 131072;       // 16384

    produce_fgh<<<256, 256, 0, stream>>>(x, w1, b1, w2, b2, w3, b3, fT, gT, hhb);
    wtz_kernel<<<142, 256, 0, stream>>>(w4, w5, w6, Wt, w6b, x2p);
    attn_kernel<<<256, 512, 0, stream>>>(fT, gT, hhb, w6b, b6, x2p, h2b);
    conv7_kernel<<<256, 448, 0, stream>>>(x2p, Wt, b4, b5, f2, g2);
    s2_softmax_kernel<<<64, 256, 0, stream>>>(f2, g2, beta2);
    o2_residual_kernel<<<256, 256, 0, stream>>>(h2b, beta2, x, out);
}

// Round 16
// 76.343 us; speedup vs baseline: 1.0276x; 1.0276x over previous
//
#include <hip/hip_runtime.h>
#include <math.h>

#define BB 4
#define CC 64
#define CRR 8
#define NN 4096

typedef __attribute__((ext_vector_type(8))) short bf16x8;
typedef __attribute__((ext_vector_type(4))) float f32x4;

__device__ inline float bf2f(ushort u) {
    union { uint i; float f; } v; v.i = (uint)u << 16; return v.f;
}
__device__ inline ushort f2bf(float f) {
    uint u = __builtin_bit_cast(uint, f);
    u = (u + 0x7FFFu + ((u >> 16) & 1u)) >> 16;
    return (ushort)u;
}
__device__ inline uint bfpack2(float a, float b) {
    uint ua = __builtin_bit_cast(uint, a);
    uint ub = __builtin_bit_cast(uint, b);
    ua = (ua + 0x7FFFu + ((ua >> 16) & 1u)) >> 16;
    ub = (ub + 0x7FFFu + ((ub >> 16) & 1u)) & 0xFFFF0000u;
    return ua | ub;
}
// 1-op truncating bf16 pair pack: bytes [b.3,b.2,a.3,a.2]
__device__ inline uint pkrtz(float a, float b) {
    return __builtin_amdgcn_perm(__builtin_bit_cast(uint, b),
                                 __builtin_bit_cast(uint, a), 0x07060302u);
}
// native 2^x (single v_exp_f32; inputs bounded |x| < 30 here)
__device__ inline float fexp2(float x) {
#if __has_builtin(__builtin_amdgcn_exp2f)
    return __builtin_amdgcn_exp2f(x);
#else
    float r; asm("v_exp_f32 %0, %1" : "=v"(r) : "v"(x)); return r;
#endif
}

// x2p padded pixel-major: [b][py 70][px 70][ci 64] bf16, pad=3
#define X2P_B 313600   // 70*70*64

// ---------------------------------------------------------------------------
// Producer: f = conv1x1(x,w1,b1) * log2(e), g = conv1x1(x,w2,b2),
//           hh = conv1x1(x,w3,b3).  b = bid&3 (XCD-local batches).
// ---------------------------------------------------------------------------
__global__ __launch_bounds__(256) void produce_fgh(
    const float* __restrict__ x,
    const float* __restrict__ w1, const float* __restrict__ b1,
    const float* __restrict__ w2, const float* __restrict__ b2,
    const float* __restrict__ w3, const float* __restrict__ b3,
    ushort* __restrict__ fT, ushort* __restrict__ gT, ushort* __restrict__ hhb)
{
    const float LOG2E = 1.4426950408889634f;
    int t = threadIdx.x;
    int b = blockIdx.x & 3;
    int n = ((blockIdx.x >> 2) << 6) + (t & 63);
    int og = __builtin_amdgcn_readfirstlane(t >> 6);  // wave-uniform

    const float* xb = x + ((size_t)b << 18) + n;
    float xv[64];
#pragma unroll
    for (int c = 0; c < 64; ++c) xv[c] = xb[(size_t)c << 12];

    if (og == 0) {
        ushort fo[8], go[8];
#pragma unroll
        for (int k = 0; k < 8; ++k) {
            float a1 = b1[k], a2 = b2[k];
#pragma unroll
            for (int c = 0; c < 64; ++c) {
                a1 = fmaf(w1[k * 64 + c], xv[c], a1);
                a2 = fmaf(w2[k * 64 + c], xv[c], a2);
            }
            fo[k] = f2bf(a1 * LOG2E); go[k] = f2bf(a2);
        }
        uint4 fq = make_uint4((uint)fo[0] | ((uint)fo[1] << 16),
                              (uint)fo[2] | ((uint)fo[3] << 16),
                              (uint)fo[4] | ((uint)fo[5] << 16),
                              (uint)fo[6] | ((uint)fo[7] << 16));
        uint4 gq = make_uint4((uint)go[0] | ((uint)go[1] << 16),
                              (uint)go[2] | ((uint)go[3] << 16),
                              (uint)go[4] | ((uint)go[5] << 16),
                              (uint)go[6] | ((uint)go[7] << 16));
        *(uint4*)&fT[((size_t)b << 15) + (size_t)n * 8] = fq;
        *(uint4*)&gT[((size_t)b << 15) + (size_t)n * 8] = gq;
#pragma unroll
        for (int k = 0; k < 4; ++k) {
            float a = b3[k];
#pragma unroll
            for (int c = 0; c < 64; ++c) a = fmaf(w3[k * 64 + c], xv[c], a);
            hhb[((size_t)b << 18) + ((size_t)k << 12) + n] = f2bf(a);
        }
    } else {
        int c0 = og * 20 - 16;  // 4, 24, 44
#pragma unroll
        for (int k = 0; k < 20; ++k) {
            float a = b3[c0 + k];
#pragma unroll
            for (int c = 0; c < 64; ++c) a = fmaf(w3[(c0 + k) * 64 + c], xv[c], a);
            hhb[((size_t)b << 18) + ((size_t)(c0 + k) << 12) + n] = f2bf(a);
        }
    }
}

// ---------------------------------------------------------------------------
// Weight transform + w6->bf16 + x2p halo zero, one kernel.
// ---------------------------------------------------------------------------
__global__ __launch_bounds__(256) void wtz_kernel(
    const float* __restrict__ w4, const float* __restrict__ w5,
    const float* __restrict__ w6,
    ushort* __restrict__ Wt, ushort* __restrict__ w6b, ushort* __restrict__ x2p)
{
    int bid = blockIdx.x;
    int t = threadIdx.x;
    if (bid < 128) {
        int conv = bid >> 6, co = bid & 63;
        const float* W = conv ? w5 : w4;
        for (int i = t; i < 3136; i += 256) {
            int ci = i / 49, kk = i - ci * 49;
            Wt[(((size_t)(conv * 64 + co)) * 49 + kk) * 64 + ci] = f2bf(W[co * 3136 + i]);
        }
    } else if (bid == 128) {
#pragma unroll
        for (int k = 0; k < 16; ++k) {
            int i = k * 256 + t;
            w6b[i] = f2bf(w6[i]);
        }
    } else {
        int gid = (bid - 129) * 256 + t;
        if (gid >= 4 * 804) return;
        int b = gid / 804;
        int i = gid - b * 804;
        int py, px;
        if (i < 210) { py = i / 70; px = i - py * 70; }
        else if (i < 420) { int j = i - 210; int r = j / 70; py = 67 + r; px = j - r * 70; }
        else { int j = i - 420; int r = j / 6; py = 3 + r; int c = j - r * 6; px = c < 3 ? c : 64 + c; }
        ushort* p = x2p + (size_t)b * X2P_B + (size_t)(py * 70 + px) * 64;
        uint4 z = make_uint4(0, 0, 0, 0);
#pragma unroll
        for (int k = 0; k < 8; ++k) *(uint4*)(p + k * 8) = z;
    }
}

// ---------------------------------------------------------------------------
// Fused MFMA flash attention + h2 epilogue (R13 structure — measured best).
// 1024 threads = 16 waves = 4 n-quads x 4 m-strips, double-buffered hh.
// ---------------------------------------------------------------------------
__global__ __launch_bounds__(1024) void attn_kernel(
    const ushort* __restrict__ fT, const ushort* __restrict__ gT,
    const ushort* __restrict__ hhb, const ushort* __restrict__ w6b,
    const float* __restrict__ b6,
    ushort* __restrict__ x2p, ushort* __restrict__ h2b)
{
    __shared__ __align__(16) char smem[98304];
    ushort* hhT = (ushort*)smem;                 // [4 quad][2 buf][4096]  64 KB
    ushort* PstB = (ushort*)(smem + 65536);      // [16 wave][1024]        32 KB
    float* Acc = (float*)smem;                   // [4 q][64 m][68] (combine)
    float* Lq  = (float*)(smem + 69632);         // [4][64]
    ushort* x2s = (ushort*)(smem + 70656);       // [64 m][72]

    int t = threadIdx.x;
    int q = t >> 8, tq = t & 255;
    int l = t & 63;
    int wq = tq >> 6;
    int w16 = t >> 6;
    int ml = l & 15, g = l >> 4;
    int b = blockIdx.x & 3;                      // XCD-local batch
    int mt = blockIdx.x >> 2;
    int m0 = mt << 6;
    int col = m0 + wq * 16 + ml;

    const ushort* fTb = fT + ((size_t)b << 15) + (size_t)q * 8192;
    const ushort* gTb = gT + ((size_t)b << 15);
    const ushort* hhB = hhb + ((size_t)b << 18) + (q << 10);

    const bf16x8 z8 = {0, 0, 0, 0, 0, 0, 0, 0};
    const f32x4 z4 = {0.f, 0.f, 0.f, 0.f};

    bf16x8 gfrag = *(const bf16x8*)(gTb + (size_t)col * 8);
    if (g != 0) gfrag = z8;

    int sc = tq >> 2, sp = tq & 3;
    const ushort* hrowBase = hhB + (size_t)sc * 4096 + sp * 16;
    int hdst = q * 8192 + sp * 1024 + sc * 8;

    uint4 h0 = *(const uint4*)(hrowBase);
    uint4 h1 = *(const uint4*)(hrowBase + 8);
    *(uint4*)&hhT[hdst] = h0;
    *(uint4*)&hhT[hdst + 512] = h1;
    bf16x8 afc[4];
#pragma unroll
    for (int s = 0; s < 4; ++s)
        afc[s] = *(const bf16x8*)(fTb + (size_t)(16 * s + ml) * 8);

    f32x4 acc[4] = {z4, z4, z4, z4};
    float rsum = 0.f;
    int swz = (ml & 7) << 4;
    char* pbase = (char*)PstB + w16 * 2048;
    __syncthreads();

    for (int nt = 0; nt < 16; ++nt) {
        int buf = nt & 1;
        bf16x8 afn[4];
        if (nt < 15) {
            int n0 = (nt + 1) << 6;
            h0 = *(const uint4*)(hrowBase + n0);
            h1 = *(const uint4*)(hrowBase + n0 + 8);
#pragma unroll
            for (int s = 0; s < 4; ++s)
                afn[s] = *(const bf16x8*)(fTb + (size_t)(n0 + 16 * s + ml) * 8);
        }

        f32x4 Sv[4];
#pragma unroll
        for (int s = 0; s < 4; ++s)
            Sv[s] = __builtin_amdgcn_mfma_f32_16x16x32_bf16(afc[s], gfrag, z4, 0, 0, 0);

        uint plo[4], phi[4];
#pragma unroll
        for (int s = 0; s < 4; ++s) {
            float p0 = fexp2(Sv[s][0]);
            float p1 = fexp2(Sv[s][1]);
            float p2 = fexp2(Sv[s][2]);
            float p3 = fexp2(Sv[s][3]);
            rsum += (p0 + p1) + (p2 + p3);
            plo[s] = pkrtz(p0, p1);
            phi[s] = pkrtz(p2, p3);
        }

#pragma unroll
        for (int s = 0; s < 4; ++s) {
            uint off = (uint)((ml * 128 + 32 * s + 8 * g) ^ swz);
            *(uint2*)(pbase + off) = make_uint2(plo[s], phi[s]);
        }

#pragma unroll
        for (int kk = 0; kk < 2; ++kk) {
            uint off = (uint)((ml * 128 + 64 * kk + 16 * g) ^ swz);
            bf16x8 pf = *(const bf16x8*)(pbase + off);
#pragma unroll
            for (int ct = 0; ct < 4; ++ct) {
                bf16x8 hf = *(const bf16x8*)&hhT[q * 8192 + buf * 4096 + (kk * 4 + g) * 512 + (16 * ct + ml) * 8];
                acc[ct] = __builtin_amdgcn_mfma_f32_16x16x32_bf16(hf, pf, acc[ct], 0, 0, 0);
            }
        }

        if (nt < 15) {
            int nb = (nt + 1) & 1;
            *(uint4*)&hhT[hdst + nb * 4096] = h0;
            *(uint4*)&hhT[hdst + nb * 4096 + 512] = h1;
#pragma unroll
            for (int s = 0; s < 4; ++s) afc[s] = afn[s];
        }
        __syncthreads();
    }

    rsum += __shfl_xor(rsum, 16);
    rsum += __shfl_xor(rsum, 32);

    {
        float* arow = Acc + q * 4352 + (wq * 16 + ml) * 68;
#pragma unroll
        for (int ct = 0; ct < 4; ++ct)
            *(f32x4*)(arow + 16 * ct + 4 * g) = acc[ct];
        if (g == 0) Lq[q * 64 + wq * 16 + ml] = rsum;
    }
    __syncthreads();

    {
        int m = t >> 4, c0 = (t & 15) << 2;
        float Ltot = Lq[m] + Lq[64 + m] + Lq[128 + m] + Lq[192 + m];
        float rL = 1.f / Ltot;
        f32x4 v0 = *(const f32x4*)(Acc + 0 * 4352 + m * 68 + c0);
        f32x4 v1 = *(const f32x4*)(Acc + 1 * 4352 + m * 68 + c0);
        f32x4 v2 = *(const f32x4*)(Acc + 2 * 4352 + m * 68 + c0);
        f32x4 v3 = *(const f32x4*)(Acc + 3 * 4352 + m * 68 + c0);
        f32x4 v;
#pragma unroll
        for (int r = 0; r < 4; ++r)
            v[r] = ((v0[r] + v1[r]) + (v2[r] + v3[r])) * rL;
        uint2 pk = make_uint2(bfpack2(v[0], v[1]), bfpack2(v[2], v[3]));
        int px = m + 3, py = mt + 3;
        *(uint2*)(x2p + (size_t)b * X2P_B + (size_t)(py * 70 + px) * 64 + c0) = pk;
        *(uint2*)(x2s + m * 72 + c0) = pk;
    }
    __syncthreads();

    {
        int dt = w16 & 3, mq = w16 >> 2;
        f32x4 hacc = z4;
#pragma unroll
        for (int kk = 0; kk < 2; ++kk) {
            bf16x8 xf = *(const bf16x8*)(x2s + (mq * 16 + ml) * 72 + 32 * kk + 8 * g);
            bf16x8 wf = *(const bf16x8*)(w6b + (size_t)(16 * dt + ml) * 64 + 32 * kk + 8 * g);
            hacc = __builtin_amdgcn_mfma_f32_16x16x32_bf16(wf, xf, hacc, 0, 0, 0);
        }
        ushort* h2row = h2b + ((size_t)b << 18) + (m0 + mq * 16 + ml);
#pragma unroll
        for (int r = 0; r < 4; ++r) {
            int d = 16 * dt + 4 * g + r;
            h2row[(size_t)d << 12] = f2bf(hacc[r] + b6[d]);
        }
    }
}

// ---------------------------------------------------------------------------
// 7x7 stride-4 conv, single kernel (R12 structure, unchanged).
// ---------------------------------------------------------------------------
__global__ __launch_bounds__(448) void conv7_kernel(
    const ushort* __restrict__ x2p, const ushort* __restrict__ Wt,
    const float* __restrict__ b4, const float* __restrict__ b5,
    float* __restrict__ f2, float* __restrict__ g2)
{
    __shared__ float red[7][512];   // 14 KB
    int t = threadIdx.x;
    int l = t & 63, ky = t >> 6;    // wave = ky 0..6
    int ml = l & 15, g = l >> 4;
    int bid = blockIdx.x;
    int bc = bid & 7;               // XCD-local (b,conv)
    int sub = bid >> 3;             // 0..31
    int ct = sub & 3, oh = sub >> 2;  // co-tile, 32-opix half
    int conv = bc & 1, b = bc >> 1;

    int co0 = ct * 16;
    const ushort* wb = Wt + (size_t)conv * 200704
                     + (size_t)(co0 + ml) * 3136 + (size_t)(ky * 7) * 64 + g * 8;
    const ushort* xbase = x2p + (size_t)b * X2P_B + g * 8;

    int pixoff[2];
#pragma unroll
    for (int s = 0; s < 2; ++s) {
        int opix = oh * 32 + s * 16 + ml;
        int oy = opix >> 4, ox = opix & 15;
        pixoff[s] = ((oy * 4 + ky) * 70 + ox * 4) * 64;
    }

    const f32x4 z4 = {0.f, 0.f, 0.f, 0.f};
    f32x4 acc[2] = {z4, z4};

#pragma unroll
    for (int kx = 0; kx < 7; ++kx) {
#pragma unroll
        for (int ci0 = 0; ci0 < 64; ci0 += 32) {
            bf16x8 av = *(const bf16x8*)(wb + kx * 64 + ci0);
#pragma unroll
            for (int s = 0; s < 2; ++s) {
                bf16x8 bv = *(const bf16x8*)(xbase + pixoff[s] + kx * 64 + ci0);
                acc[s] = __builtin_amdgcn_mfma_f32_16x16x32_bf16(av, bv, acc[s], 0, 0, 0);
            }
        }
    }

#pragma unroll
    for (int s = 0; s < 2; ++s)
#pragma unroll
        for (int r = 0; r < 4; ++r)
            red[ky][(4 * g + r) * 32 + s * 16 + ml] = acc[s][r];
    __syncthreads();

    const float* bias = conv ? b5 : b4;
    float* y = conv ? g2 : f2;
    for (int idx = t; idx < 512; idx += 448) {
        float s = red[0][idx];
        s += red[1][idx]; s += red[2][idx]; s += red[3][idx];
        s += red[4][idx]; s += red[5][idx]; s += red[6][idx];
        int co = co0 + (idx >> 5);
        int opix = oh * 32 + (idx & 31);
        y[((size_t)(b * 64 + co) << 8) + opix] = s + bias[co];
    }
}

// ---------------------------------------------------------------------------
// s2 + softmax, register-blocked fp32 (R13 structure, unchanged).
// ---------------------------------------------------------------------------
__global__ __launch_bounds__(256) void s2_softmax_kernel(
    const float* __restrict__ f2, const float* __restrict__ g2,
    float* __restrict__ beta2)
{
    __shared__ __align__(16) float g2t[256][8];   // [n][4d + pad] 8 KB
    __shared__ __align__(16) float part[16][64][4]; // 16 KB
    __shared__ __align__(16) float s2f[64][4];    // 1 KB
    __shared__ float mx4[4], rs4[4];
    int t = threadIdx.x;
    int b = blockIdx.x & 3;
    int d0 = (blockIdx.x >> 2) << 2;   // 4 d per wg

    {   // stage g2t[n][dd]
        int dd = t & 3, n0 = (t >> 2) << 2;
        const float* gp = g2 + ((size_t)(b * 64 + d0 + dd) << 8) + n0;
        float4 v = *(const float4*)gp;
        g2t[n0 + 0][dd] = v.x; g2t[n0 + 1][dd] = v.y;
        g2t[n0 + 2][dd] = v.z; g2t[n0 + 3][dd] = v.w;
    }
    __syncthreads();

    int c0 = (t & 15) << 2, nq = t >> 4;
    float acc[4][4];
#pragma unroll
    for (int i = 0; i < 4; ++i)
#pragma unroll
        for (int j = 0; j < 4; ++j) acc[i][j] = 0.f;
    const float* fb = f2 + ((size_t)(b * 64) << 8);
#pragma unroll 4
    for (int i = 0; i < 16; ++i) {
        int n = (nq << 4) + ((i + nq) & 15);   // staggered: bank-spread + broadcast
        float4 gv = *(const float4*)&g2t[n][0];
        float fv0 = fb[(c0 + 0) * 256 + n];
        float fv1 = fb[(c0 + 1) * 256 + n];
        float fv2 = fb[(c0 + 2) * 256 + n];
        float fv3 = fb[(c0 + 3) * 256 + n];
        acc[0][0] = fmaf(fv0, gv.x, acc[0][0]); acc[0][1] = fmaf(fv0, gv.y, acc[0][1]);
        acc[0][2] = fmaf(fv0, gv.z, acc[0][2]); acc[0][3] = fmaf(fv0, gv.w, acc[0][3]);
        acc[1][0] = fmaf(fv1, gv.x, acc[1][0]); acc[1][1] = fmaf(fv1, gv.y, acc[1][1]);
        acc[1][2] = fmaf(fv1, gv.z, acc[1][2]); acc[1][3] = fmaf(fv1, gv.w, acc[1][3]);
        acc[2][0] = fmaf(fv2, gv.x, acc[2][0]); acc[2][1] = fmaf(fv2, gv.y, acc[2][1]);
        acc[2][2] = fmaf(fv2, gv.z, acc[2][2]); acc[2][3] = fmaf(fv2, gv.w, acc[2][3]);
        acc[3][0] = fmaf(fv3, gv.x, acc[3][0]); acc[3][1] = fmaf(fv3, gv.y, acc[3][1]);
        acc[3][2] = fmaf(fv3, gv.z, acc[3][2]); acc[3][3] = fmaf(fv3, gv.w, acc[3][3]);
    }
#pragma unroll
    for (int i = 0; i < 4; ++i)
        *(float4*)&part[nq][c0 + i][0] =
            make_float4(acc[i][0], acc[i][1], acc[i][2], acc[i][3]);
    __syncthreads();

    if (t < 64) {   // reduce 16 n-partials for row c = t
        int c = t;
        float4 s = make_float4(0.f, 0.f, 0.f, 0.f);
#pragma unroll
        for (int q2 = 0; q2 < 16; ++q2) {
            float4 v = *(const float4*)&part[q2][c][0];
            s.x += v.x; s.y += v.y; s.z += v.z; s.w += v.w;
        }
        *(float4*)&s2f[c][0] = s;
    }
    __syncthreads();
    if (t < 4) {    // softmax stats over c for column d0+t
        float mxv = s2f[0][t];
        for (int c = 1; c < 64; ++c) mxv = fmaxf(mxv, s2f[c][t]);
        float sm = 0.f;
        for (int c = 0; c < 64; ++c) sm += __expf(s2f[c][t] - mxv);
        mx4[t] = mxv; rs4[t] = 1.f / sm;
    }
    __syncthreads();
    {
        int c = t >> 2, dd = t & 3;
        beta2[((size_t)b << 12) + c * 64 + d0 + dd] =
            __expf(s2f[c][dd] - mx4[dd]) * rs4[dd];
    }
}

// ---------------------------------------------------------------------------
// o2 + residual via MFMA (R13 structure, unchanged).
// ---------------------------------------------------------------------------
__global__ __launch_bounds__(256) void o2_residual_kernel(
    const ushort* __restrict__ h2b, const float* __restrict__ beta2,
    const float* __restrict__ x, float* __restrict__ out)
{
    __shared__ __align__(16) ushort bt[64][68];   // beta2^T hi  [d][c]
    __shared__ __align__(16) ushort btl[64][68];  // beta2^T lo
    __shared__ __align__(16) ushort hn[64][68];   // h2^T [n][c]
    int t = threadIdx.x;
    int b = blockIdx.x & 3;
    int n0 = (blockIdx.x >> 2) << 6;
    int l = t & 63, w = t >> 6;
    int ml = l & 15, g = l >> 4;

    {   // stage: thread c = t>>2, 16-chunk = t&3
        int c = t >> 2, o16 = (t & 3) << 4;
        const float* bp = beta2 + ((size_t)b << 12) + c * 64 + o16;
#pragma unroll
        for (int i = 0; i < 16; i += 4) {
            float4 v = *(const float4*)(bp + i);
            float vv[4] = {v.x, v.y, v.z, v.w};
#pragma unroll
            for (int k = 0; k < 4; ++k) {
                ushort hi = f2bf(vv[k]);
                bt[o16 + i + k][c] = hi;
                btl[o16 + i + k][c] = f2bf(vv[k] - bf2f(hi));
            }
        }
        const ushort* hp = h2b + ((size_t)(b * 64 + c) << 12) + n0 + o16;
#pragma unroll
        for (int i = 0; i < 16; i += 8) {
            uint4 hv = *(const uint4*)(hp + i);
            const ushort* hs = (const ushort*)&hv;
#pragma unroll
            for (int k = 0; k < 8; ++k) hn[o16 + i + k][c] = hs[k];
        }
    }
    __syncthreads();

    const f32x4 z4 = {0.f, 0.f, 0.f, 0.f};
    f32x4 acc[4] = {z4, z4, z4, z4};
#pragma unroll
    for (int kk = 0; kk < 2; ++kk) {
        bf16x8 ah = *(const bf16x8*)&bt[w * 16 + ml][kk * 32 + g * 8];
        bf16x8 al = *(const bf16x8*)&btl[w * 16 + ml][kk * 32 + g * 8];
#pragma unroll
        for (int nt = 0; nt < 4; ++nt) {
            bf16x8 bv = *(const bf16x8*)&hn[nt * 16 + ml][kk * 32 + g * 8];
            acc[nt] = __builtin_amdgcn_mfma_f32_16x16x32_bf16(ah, bv, acc[nt], 0, 0, 0);
            acc[nt] = __builtin_amdgcn_mfma_f32_16x16x32_bf16(al, bv, acc[nt], 0, 0, 0);
        }
    }

#pragma unroll
    for (int nt = 0; nt < 4; ++nt)
#pragma unroll
        for (int r = 0; r < 4; ++r) {
            int d = w * 16 + g * 4 + r;
            int n = n0 + nt * 16 + ml;
            size_t o = ((size_t)(b * 64 + d) << 12) + n;
            out[o] = acc[nt][r] + x[o];
        }
}

// ---------------------------------------------------------------------------
extern "C" void kernel_launch(void* const* d_in, const int* in_sizes, int n_in,
                              void* d_out, int out_size, void* d_ws, size_t ws_size,
                              hipStream_t stream)
{
    const float* x  = (const float*)d_in[0];
    const float* w1 = (const float*)d_in[1];
    const float* b1 = (const float*)d_in[2];
    const float* w2 = (const float*)d_in[3];
    const float* b2 = (const float*)d_in[4];
    const float* w3 = (const float*)d_in[5];
    const float* b3 = (const float*)d_in[6];
    const float* w4 = (const float*)d_in[7];
    const float* b4 = (const float*)d_in[8];
    const float* w5 = (const float*)d_in[9];
    const float* b5 = (const float*)d_in[10];
    const float* w6 = (const float*)d_in[11];
    const float* b6 = (const float*)d_in[12];
    float* out = (float*)d_out;

    ushort* u = (ushort*)d_ws;
    ushort* fT  = u;                  // 131072 elems
    ushort* gT  = fT + 131072;        // 131072
    ushort* hhb = gT + 131072;        // 1048576
    ushort* x2p = hhb + 1048576;      // 1254400 (4*70*70*64), padded
    ushort* h2b = x2p + 1254400;      // 1048576
    ushort* Wt  = h2b + 1048576;      // 401408 (2*64*49*64)
    ushort* w6b = Wt + 401408;        // 4096
    float* fr    = (float*)(w6b + 4096);
    float* f2    = fr;                // 65536
    float* g2    = fr + 65536;        // 65536
    float* beta2 = fr + 131072;       // 16384

    produce_fgh<<<256, 256, 0, stream>>>(x, w1, b1, w2, b2, w3, b3, fT, gT, hhb);
    wtz_kernel<<<142, 256, 0, stream>>>(w4, w5, w6, Wt, w6b, x2p);
    attn_kernel<<<256, 1024, 0, stream>>>(fT, gT, hhb, w6b, b6, x2p, h2b);
    conv7_kernel<<<256, 448, 0, stream>>>(x2p, Wt, b4, b5, f2, g2);
    s2_softmax_kernel<<<64, 256, 0, stream>>>(f2, g2, beta2);
    o2_residual_kernel<<<256, 256, 0, stream>>>(h2b, beta2, x, out);
}

// Round 17
// 72.711 us; speedup vs baseline: 1.0790x; 1.0500x over previous
//
#include <hip/hip_runtime.h>
#include <math.h>

#define BB 4
#define CC 64
#define CRR 8
#define NN 4096

typedef __attribute__((ext_vector_type(8))) short bf16x8;
typedef __attribute__((ext_vector_type(4))) float f32x4;

__device__ inline float bf2f(ushort u) {
    union { uint i; float f; } v; v.i = (uint)u << 16; return v.f;
}
__device__ inline ushort f2bf(float f) {
    uint u = __builtin_bit_cast(uint, f);
    u = (u + 0x7FFFu + ((u >> 16) & 1u)) >> 16;
    return (ushort)u;
}
__device__ inline uint bfpack2(float a, float b) {
    uint ua = __builtin_bit_cast(uint, a);
    uint ub = __builtin_bit_cast(uint, b);
    ua = (ua + 0x7FFFu + ((ua >> 16) & 1u)) >> 16;
    ub = (ub + 0x7FFFu + ((ub >> 16) & 1u)) & 0xFFFF0000u;
    return ua | ub;
}
// 1-op truncating bf16 pair pack: bytes [b.3,b.2,a.3,a.2]
__device__ inline uint pkrtz(float a, float b) {
    return __builtin_amdgcn_perm(__builtin_bit_cast(uint, b),
                                 __builtin_bit_cast(uint, a), 0x07060302u);
}
// native 2^x (single v_exp_f32; inputs bounded |x| < 30 here)
__device__ inline float fexp2(float x) {
#if __has_builtin(__builtin_amdgcn_exp2f)
    return __builtin_amdgcn_exp2f(x);
#else
    float r; asm("v_exp_f32 %0, %1" : "=v"(r) : "v"(x)); return r;
#endif
}

// x2p padded pixel-major: [b][py 70][px 70][ci 64] bf16, pad=3
#define X2P_B 313600   // 70*70*64

// ---------------------------------------------------------------------------
// Producer: f = conv1x1(x,w1,b1) * log2(e), g = conv1x1(x,w2,b2),
//           hh = conv1x1(x,w3,b3).  b = bid&3 (XCD-local batches).
// ---------------------------------------------------------------------------
__global__ __launch_bounds__(256) void produce_fgh(
    const float* __restrict__ x,
    const float* __restrict__ w1, const float* __restrict__ b1,
    const float* __restrict__ w2, const float* __restrict__ b2,
    const float* __restrict__ w3, const float* __restrict__ b3,
    ushort* __restrict__ fT, ushort* __restrict__ gT, ushort* __restrict__ hhb)
{
    const float LOG2E = 1.4426950408889634f;
    int t = threadIdx.x;
    int b = blockIdx.x & 3;
    int n = ((blockIdx.x >> 2) << 6) + (t & 63);
    int og = __builtin_amdgcn_readfirstlane(t >> 6);  // wave-uniform

    const float* xb = x + ((size_t)b << 18) + n;
    float xv[64];
#pragma unroll
    for (int c = 0; c < 64; ++c) xv[c] = xb[(size_t)c << 12];

    if (og == 0) {
        ushort fo[8], go[8];
#pragma unroll
        for (int k = 0; k < 8; ++k) {
            float a1 = b1[k], a2 = b2[k];
#pragma unroll
            for (int c = 0; c < 64; ++c) {
                a1 = fmaf(w1[k * 64 + c], xv[c], a1);
                a2 = fmaf(w2[k * 64 + c], xv[c], a2);
            }
            fo[k] = f2bf(a1 * LOG2E); go[k] = f2bf(a2);
        }
        uint4 fq = make_uint4((uint)fo[0] | ((uint)fo[1] << 16),
                              (uint)fo[2] | ((uint)fo[3] << 16),
                              (uint)fo[4] | ((uint)fo[5] << 16),
                              (uint)fo[6] | ((uint)fo[7] << 16));
        uint4 gq = make_uint4((uint)go[0] | ((uint)go[1] << 16),
                              (uint)go[2] | ((uint)go[3] << 16),
                              (uint)go[4] | ((uint)go[5] << 16),
                              (uint)go[6] | ((uint)go[7] << 16));
        *(uint4*)&fT[((size_t)b << 15) + (size_t)n * 8] = fq;
        *(uint4*)&gT[((size_t)b << 15) + (size_t)n * 8] = gq;
#pragma unroll
        for (int k = 0; k < 4; ++k) {
            float a = b3[k];
#pragma unroll
            for (int c = 0; c < 64; ++c) a = fmaf(w3[k * 64 + c], xv[c], a);
            hhb[((size_t)b << 18) + ((size_t)k << 12) + n] = f2bf(a);
        }
    } else {
        int c0 = og * 20 - 16;  // 4, 24, 44
#pragma unroll
        for (int k = 0; k < 20; ++k) {
            float a = b3[c0 + k];
#pragma unroll
            for (int c = 0; c < 64; ++c) a = fmaf(w3[(c0 + k) * 64 + c], xv[c], a);
            hhb[((size_t)b << 18) + ((size_t)(c0 + k) << 12) + n] = f2bf(a);
        }
    }
}

// ---------------------------------------------------------------------------
// Weight transform + w6->bf16 + x2p halo zero, one kernel.
// ---------------------------------------------------------------------------
__global__ __launch_bounds__(256) void wtz_kernel(
    const float* __restrict__ w4, const float* __restrict__ w5,
    const float* __restrict__ w6,
    ushort* __restrict__ Wt, ushort* __restrict__ w6b, ushort* __restrict__ x2p)
{
    int bid = blockIdx.x;
    int t = threadIdx.x;
    if (bid < 128) {
        int conv = bid >> 6, co = bid & 63;
        const float* W = conv ? w5 : w4;
        for (int i = t; i < 3136; i += 256) {
            int ci = i / 49, kk = i - ci * 49;
            Wt[(((size_t)(conv * 64 + co)) * 49 + kk) * 64 + ci] = f2bf(W[co * 3136 + i]);
        }
    } else if (bid == 128) {
#pragma unroll
        for (int k = 0; k < 16; ++k) {
            int i = k * 256 + t;
            w6b[i] = f2bf(w6[i]);
        }
    } else {
        int gid = (bid - 129) * 256 + t;
        if (gid >= 4 * 804) return;
        int b = gid / 804;
        int i = gid - b * 804;
        int py, px;
        if (i < 210) { py = i / 70; px = i - py * 70; }
        else if (i < 420) { int j = i - 210; int r = j / 70; py = 67 + r; px = j - r * 70; }
        else { int j = i - 420; int r = j / 6; py = 3 + r; int c = j - r * 6; px = c < 3 ? c : 64 + c; }
        ushort* p = x2p + (size_t)b * X2P_B + (size_t)(py * 70 + px) * 64;
        uint4 z = make_uint4(0, 0, 0, 0);
#pragma unroll
        for (int k = 0; k < 8; ++k) *(uint4*)(p + k * 8) = z;
    }
}

// ---------------------------------------------------------------------------
// Fused MFMA flash attention + h2 epilogue, software-pipelined (T15 rotation):
// PV(nt) runs while scores/exp/P-store for nt+1 issue from the same wave
// (independent ops -> co-issue on MFMA + VALU/TRANS pipes). P staging is
// double-buffered (per-wave private); hh double-buffered as before.
// 16 waves = 4 n-quads x 4 m-strips; one barrier/iter; math bit-identical
// to the R13 kernel. grid = B*64.
// ---------------------------------------------------------------------------
__global__ __launch_bounds__(1024) void attn_kernel(
    const ushort* __restrict__ fT, const ushort* __restrict__ gT,
    const ushort* __restrict__ hhb, const ushort* __restrict__ w6b,
    const float* __restrict__ b6,
    ushort* __restrict__ x2p, ushort* __restrict__ h2b)
{
    __shared__ __align__(16) char smem[131072];
    ushort* hhT = (ushort*)smem;                 // [4 quad][2 buf][4096]   64 KB
    ushort* PstB = (ushort*)(smem + 65536);      // [16 wave][2 buf][1024]  64 KB
    float* Acc = (float*)smem;                   // [4 q][64 m][68] (combine)
    float* Lq  = (float*)(smem + 69632);         // [4][64]
    ushort* x2s = (ushort*)(smem + 70656);       // [64 m][72]

    int t = threadIdx.x;
    int q = t >> 8, tq = t & 255;
    int l = t & 63;
    int wq = tq >> 6;
    int w16 = t >> 6;
    int ml = l & 15, g = l >> 4;
    int b = blockIdx.x & 3;                      // XCD-local batch
    int mt = blockIdx.x >> 2;
    int m0 = mt << 6;
    int col = m0 + wq * 16 + ml;

    const ushort* fTb = fT + ((size_t)b << 15) + (size_t)q * 8192;
    const ushort* gTb = gT + ((size_t)b << 15);
    const ushort* hhB = hhb + ((size_t)b << 18) + (q << 10);

    const bf16x8 z8 = {0, 0, 0, 0, 0, 0, 0, 0};
    const f32x4 z4 = {0.f, 0.f, 0.f, 0.f};

    bf16x8 gfrag = *(const bf16x8*)(gTb + (size_t)col * 8);
    if (g != 0) gfrag = z8;

    int sc = tq >> 2, sp = tq & 3;
    const ushort* hrowBase = hhB + (size_t)sc * 4096 + sp * 16;
    int hdst = q * 8192 + sp * 1024 + sc * 8;    // +4096 per hh buffer

    char* pwave = (char*)PstB + w16 * 4096;      // this wave's 2 P buffers
    int swz = (ml & 7) << 4;

    f32x4 acc[4] = {z4, z4, z4, z4};
    float rsum = 0.f;

    // ---- prologue: stage hh(0); scores(0) -> P buf0; prefetch nt=1 ----
    uint4 h0 = *(const uint4*)(hrowBase);
    uint4 h1 = *(const uint4*)(hrowBase + 8);
    *(uint4*)&hhT[hdst] = h0;
    *(uint4*)&hhT[hdst + 512] = h1;
    bf16x8 afS[4];
#pragma unroll
    for (int s = 0; s < 4; ++s)
        afS[s] = *(const bf16x8*)(fTb + (size_t)(16 * s + ml) * 8);
    __syncthreads();

    {
        f32x4 Sv[4];
#pragma unroll
        for (int s = 0; s < 4; ++s)
            Sv[s] = __builtin_amdgcn_mfma_f32_16x16x32_bf16(afS[s], gfrag, z4, 0, 0, 0);
#pragma unroll
        for (int s = 0; s < 4; ++s) {
            float p0 = fexp2(Sv[s][0]);
            float p1 = fexp2(Sv[s][1]);
            float p2 = fexp2(Sv[s][2]);
            float p3 = fexp2(Sv[s][3]);
            rsum += (p0 + p1) + (p2 + p3);
            uint off = (uint)((ml * 128 + 32 * s + 8 * g) ^ swz);
            *(uint2*)(pwave + off) = make_uint2(pkrtz(p0, p1), pkrtz(p2, p3));
        }
    }
    // prefetch nt=1 operands (consumed late in iteration 0)
    h0 = *(const uint4*)(hrowBase + 64);
    h1 = *(const uint4*)(hrowBase + 64 + 8);
#pragma unroll
    for (int s = 0; s < 4; ++s)
        afS[s] = *(const bf16x8*)(fTb + (size_t)(64 + 16 * s + ml) * 8);

    // ---- main loop: PV(nt) || scores(nt+1) ----
    for (int nt = 0; nt < 16; ++nt) {
        int buf = nt & 1;
        char* prd = pwave + buf * 2048;

        // PV(nt): inputs ready at iteration top
#pragma unroll
        for (int kk = 0; kk < 2; ++kk) {
            uint off = (uint)((ml * 128 + 64 * kk + 16 * g) ^ swz);
            bf16x8 pf = *(const bf16x8*)(prd + off);
#pragma unroll
            for (int ct = 0; ct < 4; ++ct) {
                bf16x8 hf = *(const bf16x8*)&hhT[q * 8192 + buf * 4096 + (kk * 4 + g) * 512 + (16 * ct + ml) * 8];
                acc[ct] = __builtin_amdgcn_mfma_f32_16x16x32_bf16(hf, pf, acc[ct], 0, 0, 0);
            }
        }

        if (nt < 15) {
            int nb = buf ^ 1;
            // hh(nt+1) regs -> other buffer (readers of `buf` unaffected)
            *(uint4*)&hhT[hdst + nb * 4096] = h0;
            *(uint4*)&hhT[hdst + nb * 4096 + 512] = h1;

            // scores(nt+1) -> P other buffer (independent of PV(nt))
            f32x4 Sv[4];
#pragma unroll
            for (int s = 0; s < 4; ++s)
                Sv[s] = __builtin_amdgcn_mfma_f32_16x16x32_bf16(afS[s], gfrag, z4, 0, 0, 0);
            char* pwr = pwave + nb * 2048;
#pragma unroll
            for (int s = 0; s < 4; ++s) {
                float p0 = fexp2(Sv[s][0]);
                float p1 = fexp2(Sv[s][1]);
                float p2 = fexp2(Sv[s][2]);
                float p3 = fexp2(Sv[s][3]);
                rsum += (p0 + p1) + (p2 + p3);
                uint off = (uint)((ml * 128 + 32 * s + 8 * g) ^ swz);
                *(uint2*)(pwr + off) = make_uint2(pkrtz(p0, p1), pkrtz(p2, p3));
            }

            if (nt < 14) {
                int n0 = (nt + 2) << 6;
                h0 = *(const uint4*)(hrowBase + n0);
                h1 = *(const uint4*)(hrowBase + n0 + 8);
#pragma unroll
                for (int s = 0; s < 4; ++s)
                    afS[s] = *(const bf16x8*)(fTb + (size_t)(n0 + 16 * s + ml) * 8);
            }
        }
        __syncthreads();
    }

    rsum += __shfl_xor(rsum, 16);
    rsum += __shfl_xor(rsum, 32);

    {
        float* arow = Acc + q * 4352 + (wq * 16 + ml) * 68;
#pragma unroll
        for (int ct = 0; ct < 4; ++ct)
            *(f32x4*)(arow + 16 * ct + 4 * g) = acc[ct];
        if (g == 0) Lq[q * 64 + wq * 16 + ml] = rsum;
    }
    __syncthreads();

    {
        int m = t >> 4, c0 = (t & 15) << 2;
        float Ltot = Lq[m] + Lq[64 + m] + Lq[128 + m] + Lq[192 + m];
        float rL = 1.f / Ltot;
        f32x4 v0 = *(const f32x4*)(Acc + 0 * 4352 + m * 68 + c0);
        f32x4 v1 = *(const f32x4*)(Acc + 1 * 4352 + m * 68 + c0);
        f32x4 v2 = *(const f32x4*)(Acc + 2 * 4352 + m * 68 + c0);
        f32x4 v3 = *(const f32x4*)(Acc + 3 * 4352 + m * 68 + c0);
        f32x4 v;
#pragma unroll
        for (int r = 0; r < 4; ++r)
            v[r] = ((v0[r] + v1[r]) + (v2[r] + v3[r])) * rL;
        uint2 pk = make_uint2(bfpack2(v[0], v[1]), bfpack2(v[2], v[3]));
        int px = m + 3, py = mt + 3;
        *(uint2*)(x2p + (size_t)b * X2P_B + (size_t)(py * 70 + px) * 64 + c0) = pk;
        *(uint2*)(x2s + m * 72 + c0) = pk;
    }
    __syncthreads();

    {
        int dt = w16 & 3, mq = w16 >> 2;
        f32x4 hacc = z4;
#pragma unroll
        for (int kk = 0; kk < 2; ++kk) {
            bf16x8 xf = *(const bf16x8*)(x2s + (mq * 16 + ml) * 72 + 32 * kk + 8 * g);
            bf16x8 wf = *(const bf16x8*)(w6b + (size_t)(16 * dt + ml) * 64 + 32 * kk + 8 * g);
            hacc = __builtin_amdgcn_mfma_f32_16x16x32_bf16(wf, xf, hacc, 0, 0, 0);
        }
        ushort* h2row = h2b + ((size_t)b << 18) + (m0 + mq * 16 + ml);
#pragma unroll
        for (int r = 0; r < 4; ++r) {
            int d = 16 * dt + 4 * g + r;
            h2row[(size_t)d << 12] = f2bf(hacc[r] + b6[d]);
        }
    }
}

// ---------------------------------------------------------------------------
// 7x7 stride-4 conv, single kernel (R12 structure, unchanged).
// ---------------------------------------------------------------------------
__global__ __launch_bounds__(448) void conv7_kernel(
    const ushort* __restrict__ x2p, const ushort* __restrict__ Wt,
    const float* __restrict__ b4, const float* __restrict__ b5,
    float* __restrict__ f2, float* __restrict__ g2)
{
    __shared__ float red[7][512];   // 14 KB
    int t = threadIdx.x;
    int l = t & 63, ky = t >> 6;    // wave = ky 0..6
    int ml = l & 15, g = l >> 4;
    int bid = blockIdx.x;
    int bc = bid & 7;               // XCD-local (b,conv)
    int sub = bid >> 3;             // 0..31
    int ct = sub & 3, oh = sub >> 2;  // co-tile, 32-opix half
    int conv = bc & 1, b = bc >> 1;

    int co0 = ct * 16;
    const ushort* wb = Wt + (size_t)conv * 200704
                     + (size_t)(co0 + ml) * 3136 + (size_t)(ky * 7) * 64 + g * 8;
    const ushort* xbase = x2p + (size_t)b * X2P_B + g * 8;

    int pixoff[2];
#pragma unroll
    for (int s = 0; s < 2; ++s) {
        int opix = oh * 32 + s * 16 + ml;
        int oy = opix >> 4, ox = opix & 15;
        pixoff[s] = ((oy * 4 + ky) * 70 + ox * 4) * 64;
    }

    const f32x4 z4 = {0.f, 0.f, 0.f, 0.f};
    f32x4 acc[2] = {z4, z4};

#pragma unroll
    for (int kx = 0; kx < 7; ++kx) {
#pragma unroll
        for (int ci0 = 0; ci0 < 64; ci0 += 32) {
            bf16x8 av = *(const bf16x8*)(wb + kx * 64 + ci0);
#pragma unroll
            for (int s = 0; s < 2; ++s) {
                bf16x8 bv = *(const bf16x8*)(xbase + pixoff[s] + kx * 64 + ci0);
                acc[s] = __builtin_amdgcn_mfma_f32_16x16x32_bf16(av, bv, acc[s], 0, 0, 0);
            }
        }
    }

#pragma unroll
    for (int s = 0; s < 2; ++s)
#pragma unroll
        for (int r = 0; r < 4; ++r)
            red[ky][(4 * g + r) * 32 + s * 16 + ml] = acc[s][r];
    __syncthreads();

    const float* bias = conv ? b5 : b4;
    float* y = conv ? g2 : f2;
    for (int idx = t; idx < 512; idx += 448) {
        float s = red[0][idx];
        s += red[1][idx]; s += red[2][idx]; s += red[3][idx];
        s += red[4][idx]; s += red[5][idx]; s += red[6][idx];
        int co = co0 + (idx >> 5);
        int opix = oh * 32 + (idx & 31);
        y[((size_t)(b * 64 + co) << 8) + opix] = s + bias[co];
    }
}

// ---------------------------------------------------------------------------
// s2 + softmax, register-blocked fp32 (R13 structure, unchanged).
// ---------------------------------------------------------------------------
__global__ __launch_bounds__(256) void s2_softmax_kernel(
    const float* __restrict__ f2, const float* __restrict__ g2,
    float* __restrict__ beta2)
{
    __shared__ __align__(16) float g2t[256][8];   // [n][4d + pad] 8 KB
    __shared__ __align__(16) float part[16][64][4]; // 16 KB
    __shared__ __align__(16) float s2f[64][4];    // 1 KB
    __shared__ float mx4[4], rs4[4];
    int t = threadIdx.x;
    int b = blockIdx.x & 3;
    int d0 = (blockIdx.x >> 2) << 2;   // 4 d per wg

    {   // stage g2t[n][dd]
        int dd = t & 3, n0 = (t >> 2) << 2;
        const float* gp = g2 + ((size_t)(b * 64 + d0 + dd) << 8) + n0;
        float4 v = *(const float4*)gp;
        g2t[n0 + 0][dd] = v.x; g2t[n0 + 1][dd] = v.y;
        g2t[n0 + 2][dd] = v.z; g2t[n0 + 3][dd] = v.w;
    }
    __syncthreads();

    int c0 = (t & 15) << 2, nq = t >> 4;
    float acc[4][4];
#pragma unroll
    for (int i = 0; i < 4; ++i)
#pragma unroll
        for (int j = 0; j < 4; ++j) acc[i][j] = 0.f;
    const float* fb = f2 + ((size_t)(b * 64) << 8);
#pragma unroll 4
    for (int i = 0; i < 16; ++i) {
        int n = (nq << 4) + ((i + nq) & 15);   // staggered: bank-spread + broadcast
        float4 gv = *(const float4*)&g2t[n][0];
        float fv0 = fb[(c0 + 0) * 256 + n];
        float fv1 = fb[(c0 + 1) * 256 + n];
        float fv2 = fb[(c0 + 2) * 256 + n];
        float fv3 = fb[(c0 + 3) * 256 + n];
        acc[0][0] = fmaf(fv0, gv.x, acc[0][0]); acc[0][1] = fmaf(fv0, gv.y, acc[0][1]);
        acc[0][2] = fmaf(fv0, gv.z, acc[0][2]); acc[0][3] = fmaf(fv0, gv.w, acc[0][3]);
        acc[1][0] = fmaf(fv1, gv.x, acc[1][0]); acc[1][1] = fmaf(fv1, gv.y, acc[1][1]);
        acc[1][2] = fmaf(fv1, gv.z, acc[1][2]); acc[1][3] = fmaf(fv1, gv.w, acc[1][3]);
        acc[2][0] = fmaf(fv2, gv.x, acc[2][0]); acc[2][1] = fmaf(fv2, gv.y, acc[2][1]);
        acc[2][2] = fmaf(fv2, gv.z, acc[2][2]); acc[2][3] = fmaf(fv2, gv.w, acc[2][3]);
        acc[3][0] = fmaf(fv3, gv.x, acc[3][0]); acc[3][1] = fmaf(fv3, gv.y, acc[3][1]);
        acc[3][2] = fmaf(fv3, gv.z, acc[3][2]); acc[3][3] = fmaf(fv3, gv.w, acc[3][3]);
    }
#pragma unroll
    for (int i = 0; i < 4; ++i)
        *(float4*)&part[nq][c0 + i][0] =
            make_float4(acc[i][0], acc[i][1], acc[i][2], acc[i][3]);
    __syncthreads();

    if (t < 64) {   // reduce 16 n-partials for row c = t
        int c = t;
        float4 s = make_float4(0.f, 0.f, 0.f, 0.f);
#pragma unroll
        for (int q2 = 0; q2 < 16; ++q2) {
            float4 v = *(const float4*)&part[q2][c][0];
            s.x += v.x; s.y += v.y; s.z += v.z; s.w += v.w;
        }
        *(float4*)&s2f[c][0] = s;
    }
    __syncthreads();
    if (t < 4) {    // softmax stats over c for column d0+t
        float mxv = s2f[0][t];
        for (int c = 1; c < 64; ++c) mxv = fmaxf(mxv, s2f[c][t]);
        float sm = 0.f;
        for (int c = 0; c < 64; ++c) sm += __expf(s2f[c][t] - mxv);
        mx4[t] = mxv; rs4[t] = 1.f / sm;
    }
    __syncthreads();
    {
        int c = t >> 2, dd = t & 3;
        beta2[((size_t)b << 12) + c * 64 + d0 + dd] =
            __expf(s2f[c][dd] - mx4[dd]) * rs4[dd];
    }
}

// ---------------------------------------------------------------------------
// o2 + residual via MFMA (R13 structure, unchanged).
// ---------------------------------------------------------------------------
__global__ __launch_bounds__(256) void o2_residual_kernel(
    const ushort* __restrict__ h2b, const float* __restrict__ beta2,
    const float* __restrict__ x, float* __restrict__ out)
{
    __shared__ __align__(16) ushort bt[64][68];   // beta2^T hi  [d][c]
    __shared__ __align__(16) ushort btl[64][68];  // beta2^T lo
    __shared__ __align__(16) ushort hn[64][68];   // h2^T [n][c]
    int t = threadIdx.x;
    int b = blockIdx.x & 3;
    int n0 = (blockIdx.x >> 2) << 6;
    int l = t & 63, w = t >> 6;
    int ml = l & 15, g = l >> 4;

    {   // stage: thread c = t>>2, 16-chunk = t&3
        int c = t >> 2, o16 = (t & 3) << 4;
        const float* bp = beta2 + ((size_t)b << 12) + c * 64 + o16;
#pragma unroll
        for (int i = 0; i < 16; i += 4) {
            float4 v = *(const float4*)(bp + i);
            float vv[4] = {v.x, v.y, v.z, v.w};
#pragma unroll
            for (int k = 0; k < 4; ++k) {
                ushort hi = f2bf(vv[k]);
                bt[o16 + i + k][c] = hi;
                btl[o16 + i + k][c] = f2bf(vv[k] - bf2f(hi));
            }
        }
        const ushort* hp = h2b + ((size_t)(b * 64 + c) << 12) + n0 + o16;
#pragma unroll
        for (int i = 0; i < 16; i += 8) {
            uint4 hv = *(const uint4*)(hp + i);
            const ushort* hs = (const ushort*)&hv;
#pragma unroll
            for (int k = 0; k < 8; ++k) hn[o16 + i + k][c] = hs[k];
        }
    }
    __syncthreads();

    const f32x4 z4 = {0.f, 0.f, 0.f, 0.f};
    f32x4 acc[4] = {z4, z4, z4, z4};
#pragma unroll
    for (int kk = 0; kk < 2; ++kk) {
        bf16x8 ah = *(const bf16x8*)&bt[w * 16 + ml][kk * 32 + g * 8];
        bf16x8 al = *(const bf16x8*)&btl[w * 16 + ml][kk * 32 + g * 8];
#pragma unroll
        for (int nt = 0; nt < 4; ++nt) {
            bf16x8 bv = *(const bf16x8*)&hn[nt * 16 + ml][kk * 32 + g * 8];
            acc[nt] = __builtin_amdgcn_mfma_f32_16x16x32_bf16(ah, bv, acc[nt], 0, 0, 0);
            acc[nt] = __builtin_amdgcn_mfma_f32_16x16x32_bf16(al, bv, acc[nt], 0, 0, 0);
        }
    }

#pragma unroll
    for (int nt = 0; nt < 4; ++nt)
#pragma unroll
        for (int r = 0; r < 4; ++r) {
            int d = w * 16 + g * 4 + r;
            int n = n0 + nt * 16 + ml;
            size_t o = ((size_t)(b * 64 + d) << 12) + n;
            out[o] = acc[nt][r] + x[o];
        }
}

// ---------------------------------------------------------------------------
extern "C" void kernel_launch(void* const* d_in, const int* in_sizes, int n_in,
                              void* d_out, int out_size, void* d_ws, size_t ws_size,
                              hipStream_t stream)
{
    const float* x  = (const float*)d_in[0];
    const float* w1 = (const float*)d_in[1];
    const float* b1 = (const float*)d_in[2];
    const float* w2 = (const float*)d_in[3];
    const float* b2 = (const float*)d_in[4];
    const float* w3 = (const float*)d_in[5];
    const float* b3 = (const float*)d_in[6];
    const float* w4 = (const float*)d_in[7];
    const float* b4 = (const float*)d_in[8];
    const float* w5 = (const float*)d_in[9];
    const float* b5 = (const float*)d_in[10];
    const float* w6 = (const float*)d_in[11];
    const float* b6 = (const float*)d_in[12];
    float* out = (float*)d_out;

    ushort* u = (ushort*)d_ws;
    ushort* fT  = u;                  // 131072 elems
    ushort* gT  = fT + 131072;        // 131072
    ushort* hhb = gT + 131072;        // 1048576
    ushort* x2p = hhb + 1048576;      // 1254400 (4*70*70*64), padded
    ushort* h2b = x2p + 1254400;      // 1048576
    ushort* Wt  = h2b + 1048576;      // 401408 (2*64*49*64)
    ushort* w6b = Wt + 401408;        // 4096
    float* fr    = (float*)(w6b + 4096);
    float* f2    = fr;                // 65536
    float* g2    = fr + 65536;        // 65536
    float* beta2 = fr + 131072;       // 16384

    produce_fgh<<<256, 256, 0, stream>>>(x, w1, b1, w2, b2, w3, b3, fT, gT, hhb);
    wtz_kernel<<<142, 256, 0, stream>>>(w4, w5, w6, Wt, w6b, x2p);
    attn_kernel<<<256, 1024, 0, stream>>>(fT, gT, hhb, w6b, b6, x2p, h2b);
    conv7_kernel<<<256, 448, 0, stream>>>(x2p, Wt, b4, b5, f2, g2);
    s2_softmax_kernel<<<64, 256, 0, stream>>>(f2, g2, beta2);
    o2_residual_kernel<<<256, 256, 0, stream>>>(h2b, beta2, x, out);
}

// Round 18
// 70.972 us; speedup vs baseline: 1.1054x; 1.0245x over previous
//
#include <hip/hip_runtime.h>
#include <math.h>

#define BB 4
#define CC 64
#define CRR 8
#define NN 4096

typedef __attribute__((ext_vector_type(8))) short bf16x8;
typedef __attribute__((ext_vector_type(4))) float f32x4;

__device__ inline float bf2f(ushort u) {
    union { uint i; float f; } v; v.i = (uint)u << 16; return v.f;
}
__device__ inline ushort f2bf(float f) {
    uint u = __builtin_bit_cast(uint, f);
    u = (u + 0x7FFFu + ((u >> 16) & 1u)) >> 16;
    return (ushort)u;
}
__device__ inline uint bfpack2(float a, float b) {
    uint ua = __builtin_bit_cast(uint, a);
    uint ub = __builtin_bit_cast(uint, b);
    ua = (ua + 0x7FFFu + ((ua >> 16) & 1u)) >> 16;
    ub = (ub + 0x7FFFu + ((ub >> 16) & 1u)) & 0xFFFF0000u;
    return ua | ub;
}
// 1-op truncating bf16 pair pack: bytes [b.3,b.2,a.3,a.2]
__device__ inline uint pkrtz(float a, float b) {
    return __builtin_amdgcn_perm(__builtin_bit_cast(uint, b),
                                 __builtin_bit_cast(uint, a), 0x07060302u);
}
// native 2^x (single v_exp_f32; inputs bounded |x| < 30 here)
__device__ inline float fexp2(float x) {
#if __has_builtin(__builtin_amdgcn_exp2f)
    return __builtin_amdgcn_exp2f(x);
#else
    float r; asm("v_exp_f32 %0, %1" : "=v"(r) : "v"(x)); return r;
#endif
}

// x2p padded pixel-major: [b][py 70][px 70][ci 64] bf16, pad=3
#define X2P_B 313600   // 70*70*64

// ---------------------------------------------------------------------------
// Producer: f = conv1x1(x,w1,b1) * log2(e), g = conv1x1(x,w2,b2),
//           hh = conv1x1(x,w3,b3).  b = bid&3 (XCD-local batches).
// ---------------------------------------------------------------------------
__global__ __launch_bounds__(256) void produce_fgh(
    const float* __restrict__ x,
    const float* __restrict__ w1, const float* __restrict__ b1,
    const float* __restrict__ w2, const float* __restrict__ b2,
    const float* __restrict__ w3, const float* __restrict__ b3,
    ushort* __restrict__ fT, ushort* __restrict__ gT, ushort* __restrict__ hhb)
{
    const float LOG2E = 1.4426950408889634f;
    int t = threadIdx.x;
    int b = blockIdx.x & 3;
    int n = ((blockIdx.x >> 2) << 6) + (t & 63);
    int og = __builtin_amdgcn_readfirstlane(t >> 6);  // wave-uniform

    const float* xb = x + ((size_t)b << 18) + n;
    float xv[64];
#pragma unroll
    for (int c = 0; c < 64; ++c) xv[c] = xb[(size_t)c << 12];

    if (og == 0) {
        ushort fo[8], go[8];
#pragma unroll
        for (int k = 0; k < 8; ++k) {
            float a1 = b1[k], a2 = b2[k];
#pragma unroll
            for (int c = 0; c < 64; ++c) {
                a1 = fmaf(w1[k * 64 + c], xv[c], a1);
                a2 = fmaf(w2[k * 64 + c], xv[c], a2);
            }
            fo[k] = f2bf(a1 * LOG2E); go[k] = f2bf(a2);
        }
        uint4 fq = make_uint4((uint)fo[0] | ((uint)fo[1] << 16),
                              (uint)fo[2] | ((uint)fo[3] << 16),
                              (uint)fo[4] | ((uint)fo[5] << 16),
                              (uint)fo[6] | ((uint)fo[7] << 16));
        uint4 gq = make_uint4((uint)go[0] | ((uint)go[1] << 16),
                              (uint)go[2] | ((uint)go[3] << 16),
                              (uint)go[4] | ((uint)go[5] << 16),
                              (uint)go[6] | ((uint)go[7] << 16));
        *(uint4*)&fT[((size_t)b << 15) + (size_t)n * 8] = fq;
        *(uint4*)&gT[((size_t)b << 15) + (size_t)n * 8] = gq;
#pragma unroll
        for (int k = 0; k < 4; ++k) {
            float a = b3[k];
#pragma unroll
            for (int c = 0; c < 64; ++c) a = fmaf(w3[k * 64 + c], xv[c], a);
            hhb[((size_t)b << 18) + ((size_t)k << 12) + n] = f2bf(a);
        }
    } else {
        int c0 = og * 20 - 16;  // 4, 24, 44
#pragma unroll
        for (int k = 0; k < 20; ++k) {
            float a = b3[c0 + k];
#pragma unroll
            for (int c = 0; c < 64; ++c) a = fmaf(w3[(c0 + k) * 64 + c], xv[c], a);
            hhb[((size_t)b << 18) + ((size_t)(c0 + k) << 12) + n] = f2bf(a);
        }
    }
}

// ---------------------------------------------------------------------------
// Weight transform + w6->bf16 + x2p halo zero, one kernel.
// ---------------------------------------------------------------------------
__global__ __launch_bounds__(256) void wtz_kernel(
    const float* __restrict__ w4, const float* __restrict__ w5,
    const float* __restrict__ w6,
    ushort* __restrict__ Wt, ushort* __restrict__ w6b, ushort* __restrict__ x2p)
{
    int bid = blockIdx.x;
    int t = threadIdx.x;
    if (bid < 128) {
        int conv = bid >> 6, co = bid & 63;
        const float* W = conv ? w5 : w4;
        for (int i = t; i < 3136; i += 256) {
            int ci = i / 49, kk = i - ci * 49;
            Wt[(((size_t)(conv * 64 + co)) * 49 + kk) * 64 + ci] = f2bf(W[co * 3136 + i]);
        }
    } else if (bid == 128) {
#pragma unroll
        for (int k = 0; k < 16; ++k) {
            int i = k * 256 + t;
            w6b[i] = f2bf(w6[i]);
        }
    } else {
        int gid = (bid - 129) * 256 + t;
        if (gid >= 4 * 804) return;
        int b = gid / 804;
        int i = gid - b * 804;
        int py, px;
        if (i < 210) { py = i / 70; px = i - py * 70; }
        else if (i < 420) { int j = i - 210; int r = j / 70; py = 67 + r; px = j - r * 70; }
        else { int j = i - 420; int r = j / 6; py = 3 + r; int c = j - r * 6; px = c < 3 ? c : 64 + c; }
        ushort* p = x2p + (size_t)b * X2P_B + (size_t)(py * 70 + px) * 64;
        uint4 z = make_uint4(0, 0, 0, 0);
#pragma unroll
        for (int k = 0; k < 8; ++k) *(uint4*)(p + k * 8) = z;
    }
}

// ---------------------------------------------------------------------------
// Fused MFMA flash attention + h2 epilogue, software-pipelined (R17) with
// s_setprio(1) around the MFMA clusters (T5: waves drift within an iteration
// between MFMA and exp/VALU phases -> priority arbitration pays).
// ---------------------------------------------------------------------------
__global__ __launch_bounds__(1024) void attn_kernel(
    const ushort* __restrict__ fT, const ushort* __restrict__ gT,
    const ushort* __restrict__ hhb, const ushort* __restrict__ w6b,
    const float* __restrict__ b6,
    ushort* __restrict__ x2p, ushort* __restrict__ h2b)
{
    __shared__ __align__(16) char smem[131072];
    ushort* hhT = (ushort*)smem;                 // [4 quad][2 buf][4096]   64 KB
    ushort* PstB = (ushort*)(smem + 65536);      // [16 wave][2 buf][1024]  64 KB
    float* Acc = (float*)smem;                   // [4 q][64 m][68] (combine)
    float* Lq  = (float*)(smem + 69632);         // [4][64]
    ushort* x2s = (ushort*)(smem + 70656);       // [64 m][72]

    int t = threadIdx.x;
    int q = t >> 8, tq = t & 255;
    int l = t & 63;
    int wq = tq >> 6;
    int w16 = t >> 6;
    int ml = l & 15, g = l >> 4;
    int b = blockIdx.x & 3;                      // XCD-local batch
    int mt = blockIdx.x >> 2;
    int m0 = mt << 6;
    int col = m0 + wq * 16 + ml;

    const ushort* fTb = fT + ((size_t)b << 15) + (size_t)q * 8192;
    const ushort* gTb = gT + ((size_t)b << 15);
    const ushort* hhB = hhb + ((size_t)b << 18) + (q << 10);

    const bf16x8 z8 = {0, 0, 0, 0, 0, 0, 0, 0};
    const f32x4 z4 = {0.f, 0.f, 0.f, 0.f};

    bf16x8 gfrag = *(const bf16x8*)(gTb + (size_t)col * 8);
    if (g != 0) gfrag = z8;

    int sc = tq >> 2, sp = tq & 3;
    const ushort* hrowBase = hhB + (size_t)sc * 4096 + sp * 16;
    int hdst = q * 8192 + sp * 1024 + sc * 8;    // +4096 per hh buffer

    char* pwave = (char*)PstB + w16 * 4096;      // this wave's 2 P buffers
    int swz = (ml & 7) << 4;

    f32x4 acc[4] = {z4, z4, z4, z4};
    float rsum = 0.f;

    // ---- prologue: stage hh(0); scores(0) -> P buf0; prefetch nt=1 ----
    uint4 h0 = *(const uint4*)(hrowBase);
    uint4 h1 = *(const uint4*)(hrowBase + 8);
    *(uint4*)&hhT[hdst] = h0;
    *(uint4*)&hhT[hdst + 512] = h1;
    bf16x8 afS[4];
#pragma unroll
    for (int s = 0; s < 4; ++s)
        afS[s] = *(const bf16x8*)(fTb + (size_t)(16 * s + ml) * 8);
    __syncthreads();

    {
        f32x4 Sv[4];
#pragma unroll
        for (int s = 0; s < 4; ++s)
            Sv[s] = __builtin_amdgcn_mfma_f32_16x16x32_bf16(afS[s], gfrag, z4, 0, 0, 0);
#pragma unroll
        for (int s = 0; s < 4; ++s) {
            float p0 = fexp2(Sv[s][0]);
            float p1 = fexp2(Sv[s][1]);
            float p2 = fexp2(Sv[s][2]);
            float p3 = fexp2(Sv[s][3]);
            rsum += (p0 + p1) + (p2 + p3);
            uint off = (uint)((ml * 128 + 32 * s + 8 * g) ^ swz);
            *(uint2*)(pwave + off) = make_uint2(pkrtz(p0, p1), pkrtz(p2, p3));
        }
    }
    // prefetch nt=1 operands (consumed late in iteration 0)
    h0 = *(const uint4*)(hrowBase + 64);
    h1 = *(const uint4*)(hrowBase + 64 + 8);
#pragma unroll
    for (int s = 0; s < 4; ++s)
        afS[s] = *(const bf16x8*)(fTb + (size_t)(64 + 16 * s + ml) * 8);

    // ---- main loop: PV(nt) || scores(nt+1) ----
    for (int nt = 0; nt < 16; ++nt) {
        int buf = nt & 1;
        char* prd = pwave + buf * 2048;

        // PV(nt): inputs ready at iteration top
        __builtin_amdgcn_s_setprio(1);
#pragma unroll
        for (int kk = 0; kk < 2; ++kk) {
            uint off = (uint)((ml * 128 + 64 * kk + 16 * g) ^ swz);
            bf16x8 pf = *(const bf16x8*)(prd + off);
#pragma unroll
            for (int ct = 0; ct < 4; ++ct) {
                bf16x8 hf = *(const bf16x8*)&hhT[q * 8192 + buf * 4096 + (kk * 4 + g) * 512 + (16 * ct + ml) * 8];
                acc[ct] = __builtin_amdgcn_mfma_f32_16x16x32_bf16(hf, pf, acc[ct], 0, 0, 0);
            }
        }
        __builtin_amdgcn_s_setprio(0);

        if (nt < 15) {
            int nb = buf ^ 1;
            // hh(nt+1) regs -> other buffer (readers of `buf` unaffected)
            *(uint4*)&hhT[hdst + nb * 4096] = h0;
            *(uint4*)&hhT[hdst + nb * 4096 + 512] = h1;

            // scores(nt+1) -> P other buffer (independent of PV(nt))
            f32x4 Sv[4];
            __builtin_amdgcn_s_setprio(1);
#pragma unroll
            for (int s = 0; s < 4; ++s)
                Sv[s] = __builtin_amdgcn_mfma_f32_16x16x32_bf16(afS[s], gfrag, z4, 0, 0, 0);
            __builtin_amdgcn_s_setprio(0);
            char* pwr = pwave + nb * 2048;
#pragma unroll
            for (int s = 0; s < 4; ++s) {
                float p0 = fexp2(Sv[s][0]);
                float p1 = fexp2(Sv[s][1]);
                float p2 = fexp2(Sv[s][2]);
                float p3 = fexp2(Sv[s][3]);
                rsum += (p0 + p1) + (p2 + p3);
                uint off = (uint)((ml * 128 + 32 * s + 8 * g) ^ swz);
                *(uint2*)(pwr + off) = make_uint2(pkrtz(p0, p1), pkrtz(p2, p3));
            }

            if (nt < 14) {
                int n0 = (nt + 2) << 6;
                h0 = *(const uint4*)(hrowBase + n0);
                h1 = *(const uint4*)(hrowBase + n0 + 8);
#pragma unroll
                for (int s = 0; s < 4; ++s)
                    afS[s] = *(const bf16x8*)(fTb + (size_t)(n0 + 16 * s + ml) * 8);
            }
        }
        __syncthreads();
    }

    rsum += __shfl_xor(rsum, 16);
    rsum += __shfl_xor(rsum, 32);

    {
        float* arow = Acc + q * 4352 + (wq * 16 + ml) * 68;
#pragma unroll
        for (int ct = 0; ct < 4; ++ct)
            *(f32x4*)(arow + 16 * ct + 4 * g) = acc[ct];
        if (g == 0) Lq[q * 64 + wq * 16 + ml] = rsum;
    }
    __syncthreads();

    {
        int m = t >> 4, c0 = (t & 15) << 2;
        float Ltot = Lq[m] + Lq[64 + m] + Lq[128 + m] + Lq[192 + m];
        float rL = 1.f / Ltot;
        f32x4 v0 = *(const f32x4*)(Acc + 0 * 4352 + m * 68 + c0);
        f32x4 v1 = *(const f32x4*)(Acc + 1 * 4352 + m * 68 + c0);
        f32x4 v2 = *(const f32x4*)(Acc + 2 * 4352 + m * 68 + c0);
        f32x4 v3 = *(const f32x4*)(Acc + 3 * 4352 + m * 68 + c0);
        f32x4 v;
#pragma unroll
        for (int r = 0; r < 4; ++r)
            v[r] = ((v0[r] + v1[r]) + (v2[r] + v3[r])) * rL;
        uint2 pk = make_uint2(bfpack2(v[0], v[1]), bfpack2(v[2], v[3]));
        int px = m + 3, py = mt + 3;
        *(uint2*)(x2p + (size_t)b * X2P_B + (size_t)(py * 70 + px) * 64 + c0) = pk;
        *(uint2*)(x2s + m * 72 + c0) = pk;
    }
    __syncthreads();

    {
        int dt = w16 & 3, mq = w16 >> 2;
        f32x4 hacc = z4;
#pragma unroll
        for (int kk = 0; kk < 2; ++kk) {
            bf16x8 xf = *(const bf16x8*)(x2s + (mq * 16 + ml) * 72 + 32 * kk + 8 * g);
            bf16x8 wf = *(const bf16x8*)(w6b + (size_t)(16 * dt + ml) * 64 + 32 * kk + 8 * g);
            hacc = __builtin_amdgcn_mfma_f32_16x16x32_bf16(wf, xf, hacc, 0, 0, 0);
        }
        ushort* h2row = h2b + ((size_t)b << 18) + (m0 + mq * 16 + ml);
#pragma unroll
        for (int r = 0; r < 4; ++r) {
            int d = 16 * dt + 4 * g + r;
            h2row[(size_t)d << 12] = f2bf(hacc[r] + b6[d]);
        }
    }
}

// ---------------------------------------------------------------------------
// 7x7 stride-4 conv, single kernel (R12 structure, unchanged).
// ---------------------------------------------------------------------------
__global__ __launch_bounds__(448) void conv7_kernel(
    const ushort* __restrict__ x2p, const ushort* __restrict__ Wt,
    const float* __restrict__ b4, const float* __restrict__ b5,
    float* __restrict__ f2, float* __restrict__ g2)
{
    __shared__ float red[7][512];   // 14 KB
    int t = threadIdx.x;
    int l = t & 63, ky = t >> 6;    // wave = ky 0..6
    int ml = l & 15, g = l >> 4;
    int bid = blockIdx.x;
    int bc = bid & 7;               // XCD-local (b,conv)
    int sub = bid >> 3;             // 0..31
    int ct = sub & 3, oh = sub >> 2;  // co-tile, 32-opix half
    int conv = bc & 1, b = bc >> 1;

    int co0 = ct * 16;
    const ushort* wb = Wt + (size_t)conv * 200704
                     + (size_t)(co0 + ml) * 3136 + (size_t)(ky * 7) * 64 + g * 8;
    const ushort* xbase = x2p + (size_t)b * X2P_B + g * 8;

    int pixoff[2];
#pragma unroll
    for (int s = 0; s < 2; ++s) {
        int opix = oh * 32 + s * 16 + ml;
        int oy = opix >> 4, ox = opix & 15;
        pixoff[s] = ((oy * 4 + ky) * 70 + ox * 4) * 64;
    }

    const f32x4 z4 = {0.f, 0.f, 0.f, 0.f};
    f32x4 acc[2] = {z4, z4};

#pragma unroll
    for (int kx = 0; kx < 7; ++kx) {
#pragma unroll
        for (int ci0 = 0; ci0 < 64; ci0 += 32) {
            bf16x8 av = *(const bf16x8*)(wb + kx * 64 + ci0);
#pragma unroll
            for (int s = 0; s < 2; ++s) {
                bf16x8 bv = *(const bf16x8*)(xbase + pixoff[s] + kx * 64 + ci0);
                acc[s] = __builtin_amdgcn_mfma_f32_16x16x32_bf16(av, bv, acc[s], 0, 0, 0);
            }
        }
    }

#pragma unroll
    for (int s = 0; s < 2; ++s)
#pragma unroll
        for (int r = 0; r < 4; ++r)
            red[ky][(4 * g + r) * 32 + s * 16 + ml] = acc[s][r];
    __syncthreads();

    const float* bias = conv ? b5 : b4;
    float* y = conv ? g2 : f2;
    for (int idx = t; idx < 512; idx += 448) {
        float s = red[0][idx];
        s += red[1][idx]; s += red[2][idx]; s += red[3][idx];
        s += red[4][idx]; s += red[5][idx]; s += red[6][idx];
        int co = co0 + (idx >> 5);
        int opix = oh * 32 + (idx & 31);
        y[((size_t)(b * 64 + co) << 8) + opix] = s + bias[co];
    }
}

// ---------------------------------------------------------------------------
// s2 + softmax, register-blocked fp32 (R13 structure, unchanged).
// ---------------------------------------------------------------------------
__global__ __launch_bounds__(256) void s2_softmax_kernel(
    const float* __restrict__ f2, const float* __restrict__ g2,
    float* __restrict__ beta2)
{
    __shared__ __align__(16) float g2t[256][8];   // [n][4d + pad] 8 KB
    __shared__ __align__(16) float part[16][64][4]; // 16 KB
    __shared__ __align__(16) float s2f[64][4];    // 1 KB
    __shared__ float mx4[4], rs4[4];
    int t = threadIdx.x;
    int b = blockIdx.x & 3;
    int d0 = (blockIdx.x >> 2) << 2;   // 4 d per wg

    {   // stage g2t[n][dd]
        int dd = t & 3, n0 = (t >> 2) << 2;
        const float* gp = g2 + ((size_t)(b * 64 + d0 + dd) << 8) + n0;
        float4 v = *(const float4*)gp;
        g2t[n0 + 0][dd] = v.x; g2t[n0 + 1][dd] = v.y;
        g2t[n0 + 2][dd] = v.z; g2t[n0 + 3][dd] = v.w;
    }
    __syncthreads();

    int c0 = (t & 15) << 2, nq = t >> 4;
    float acc[4][4];
#pragma unroll
    for (int i = 0; i < 4; ++i)
#pragma unroll
        for (int j = 0; j < 4; ++j) acc[i][j] = 0.f;
    const float* fb = f2 + ((size_t)(b * 64) << 8);
#pragma unroll 4
    for (int i = 0; i < 16; ++i) {
        int n = (nq << 4) + ((i + nq) & 15);   // staggered: bank-spread + broadcast
        float4 gv = *(const float4*)&g2t[n][0];
        float fv0 = fb[(c0 + 0) * 256 + n];
        float fv1 = fb[(c0 + 1) * 256 + n];
        float fv2 = fb[(c0 + 2) * 256 + n];
        float fv3 = fb[(c0 + 3) * 256 + n];
        acc[0][0] = fmaf(fv0, gv.x, acc[0][0]); acc[0][1] = fmaf(fv0, gv.y, acc[0][1]);
        acc[0][2] = fmaf(fv0, gv.z, acc[0][2]); acc[0][3] = fmaf(fv0, gv.w, acc[0][3]);
        acc[1][0] = fmaf(fv1, gv.x, acc[1][0]); acc[1][1] = fmaf(fv1, gv.y, acc[1][1]);
        acc[1][2] = fmaf(fv1, gv.z, acc[1][2]); acc[1][3] = fmaf(fv1, gv.w, acc[1][3]);
        acc[2][0] = fmaf(fv2, gv.x, acc[2][0]); acc[2][1] = fmaf(fv2, gv.y, acc[2][1]);
        acc[2][2] = fmaf(fv2, gv.z, acc[2][2]); acc[2][3] = fmaf(fv2, gv.w, acc[2][3]);
        acc[3][0] = fmaf(fv3, gv.x, acc[3][0]); acc[3][1] = fmaf(fv3, gv.y, acc[3][1]);
        acc[3][2] = fmaf(fv3, gv.z, acc[3][2]); acc[3][3] = fmaf(fv3, gv.w, acc[3][3]);
    }
#pragma unroll
    for (int i = 0; i < 4; ++i)
        *(float4*)&part[nq][c0 + i][0] =
            make_float4(acc[i][0], acc[i][1], acc[i][2], acc[i][3]);
    __syncthreads();

    if (t < 64) {   // reduce 16 n-partials for row c = t
        int c = t;
        float4 s = make_float4(0.f, 0.f, 0.f, 0.f);
#pragma unroll
        for (int q2 = 0; q2 < 16; ++q2) {
            float4 v = *(const float4*)&part[q2][c][0];
            s.x += v.x; s.y += v.y; s.z += v.z; s.w += v.w;
        }
        *(float4*)&s2f[c][0] = s;
    }
    __syncthreads();
    if (t < 4) {    // softmax stats over c for column d0+t
        float mxv = s2f[0][t];
        for (int c = 1; c < 64; ++c) mxv = fmaxf(mxv, s2f[c][t]);
        float sm = 0.f;
        for (int c = 0; c < 64; ++c) sm += __expf(s2f[c][t] - mxv);
        mx4[t] = mxv; rs4[t] = 1.f / sm;
    }
    __syncthreads();
    {
        int c = t >> 2, dd = t & 3;
        beta2[((size_t)b << 12) + c * 64 + d0 + dd] =
            __expf(s2f[c][dd] - mx4[dd]) * rs4[dd];
    }
}

// ---------------------------------------------------------------------------
// o2 + residual via MFMA (R13 structure, unchanged).
// ---------------------------------------------------------------------------
__global__ __launch_bounds__(256) void o2_residual_kernel(
    const ushort* __restrict__ h2b, const float* __restrict__ beta2,
    const float* __restrict__ x, float* __restrict__ out)
{
    __shared__ __align__(16) ushort bt[64][68];   // beta2^T hi  [d][c]
    __shared__ __align__(16) ushort btl[64][68];  // beta2^T lo
    __shared__ __align__(16) ushort hn[64][68];   // h2^T [n][c]
    int t = threadIdx.x;
    int b = blockIdx.x & 3;
    int n0 = (blockIdx.x >> 2) << 6;
    int l = t & 63, w = t >> 6;
    int ml = l & 15, g = l >> 4;

    {   // stage: thread c = t>>2, 16-chunk = t&3
        int c = t >> 2, o16 = (t & 3) << 4;
        const float* bp = beta2 + ((size_t)b << 12) + c * 64 + o16;
#pragma unroll
        for (int i = 0; i < 16; i += 4) {
            float4 v = *(const float4*)(bp + i);
            float vv[4] = {v.x, v.y, v.z, v.w};
#pragma unroll
            for (int k = 0; k < 4; ++k) {
                ushort hi = f2bf(vv[k]);
                bt[o16 + i + k][c] = hi;
                btl[o16 + i + k][c] = f2bf(vv[k] - bf2f(hi));
            }
        }
        const ushort* hp = h2b + ((size_t)(b * 64 + c) << 12) + n0 + o16;
#pragma unroll
        for (int i = 0; i < 16; i += 8) {
            uint4 hv = *(const uint4*)(hp + i);
            const ushort* hs = (const ushort*)&hv;
#pragma unroll
            for (int k = 0; k < 8; ++k) hn[o16 + i + k][c] = hs[k];
        }
    }
    __syncthreads();

    const f32x4 z4 = {0.f, 0.f, 0.f, 0.f};
    f32x4 acc[4] = {z4, z4, z4, z4};
#pragma unroll
    for (int kk = 0; kk < 2; ++kk) {
        bf16x8 ah = *(const bf16x8*)&bt[w * 16 + ml][kk * 32 + g * 8];
        bf16x8 al = *(const bf16x8*)&btl[w * 16 + ml][kk * 32 + g * 8];
#pragma unroll
        for (int nt = 0; nt < 4; ++nt) {
            bf16x8 bv = *(const bf16x8*)&hn[nt * 16 + ml][kk * 32 + g * 8];
            acc[nt] = __builtin_amdgcn_mfma_f32_16x16x32_bf16(ah, bv, acc[nt], 0, 0, 0);
            acc[nt] = __builtin_amdgcn_mfma_f32_16x16x32_bf16(al, bv, acc[nt], 0, 0, 0);
        }
    }

#pragma unroll
    for (int nt = 0; nt < 4; ++nt)
#pragma unroll
        for (int r = 0; r < 4; ++r) {
            int d = w * 16 + g * 4 + r;
            int n = n0 + nt * 16 + ml;
            size_t o = ((size_t)(b * 64 + d) << 12) + n;
            out[o] = acc[nt][r] + x[o];
        }
}

// ---------------------------------------------------------------------------
extern "C" void kernel_launch(void* const* d_in, const int* in_sizes, int n_in,
                              void* d_out, int out_size, void* d_ws, size_t ws_size,
                              hipStream_t stream)
{
    const float* x  = (const float*)d_in[0];
    const float* w1 = (const float*)d_in[1];
    const float* b1 = (const float*)d_in[2];
    const float* w2 = (const float*)d_in[3];
    const float* b2 = (const float*)d_in[4];
    const float* w3 = (const float*)d_in[5];
    const float* b3 = (const float*)d_in[6];
    const float* w4 = (const float*)d_in[7];
    const float* b4 = (const float*)d_in[8];
    const float* w5 = (const float*)d_in[9];
    const float* b5 = (const float*)d_in[10];
    const float* w6 = (const float*)d_in[11];
    const float* b6 = (const float*)d_in[12];
    float* out = (float*)d_out;

    ushort* u = (ushort*)d_ws;
    ushort* fT  = u;                  // 131072 elems
    ushort* gT  = fT + 131072;        // 131072
    ushort* hhb = gT + 131072;        // 1048576
    ushort* x2p = hhb + 1048576;      // 1254400 (4*70*70*64), padded
    ushort* h2b = x2p + 1254400;      // 1048576
    ushort* Wt  = h2b + 1048576;      // 401408 (2*64*49*64)
    ushort* w6b = Wt + 401408;        // 4096
    float* fr    = (float*)(w6b + 4096);
    float* f2    = fr;                // 65536
    float* g2    = fr + 65536;        // 65536
    float* beta2 = fr + 131072;       // 16384

    produce_fgh<<<256, 256, 0, stream>>>(x, w1, b1, w2, b2, w3, b3, fT, gT, hhb);
    wtz_kernel<<<142, 256, 0, stream>>>(w4, w5, w6, Wt, w6b, x2p);
    attn_kernel<<<256, 1024, 0, stream>>>(fT, gT, hhb, w6b, b6, x2p, h2b);
    conv7_kernel<<<256, 448, 0, stream>>>(x2p, Wt, b4, b5, f2, g2);
    s2_softmax_kernel<<<BB * 16, 256, 0, stream>>>(f2, g2, beta2);
    o2_residual_kernel<<<256, 256, 0, stream>>>(h2b, beta2, x, out);
}